// Round 7
// baseline (651.152 us; speedup 1.0000x reference)
//
#include <hip/hip_runtime.h>
#include <hip/hip_cooperative_groups.h>
#include <hip/hip_bf16.h>
#include <math.h>

namespace cg = cooperative_groups;

// Problem constants (DeepseekV3MoE reference)
#define T_TOK 2048
#define H_DIM 1024
#define E_EXP 16
#define K_TOP 4
#define G_GRP 4
#define I_SZ 512
#define SCALE_F 2.5f

#define GRID_C 1024           // 4 blocks/CU x 256 CU co-resident (LDS 34816*4 <= 160K)

typedef __attribute__((ext_vector_type(8))) short bfrag;    // 8 bf16 (4 VGPR)
typedef __attribute__((ext_vector_type(4))) float f32x4;    // MFMA acc

#define MFMA16(a, b, c) __builtin_amdgcn_mfma_f32_16x16x32_bf16(a, b, c, 0, 0, 0)

__device__ __forceinline__ short f2bf(float f) {
    union { float f; unsigned u; } v; v.f = f;
    unsigned u = v.u;
    u += 0x7fffu + ((u >> 16) & 1u);   // RNE
    return (short)(u >> 16);
}

// XOR-swizzled LDS index for 64-short rows (verified conflict-free).
__device__ __forceinline__ int lds_idx(int row, int k) {
    return row * 64 + ((((k >> 3) ^ (row & 7))) << 3) + (k & 7);
}

typedef __attribute__((address_space(1))) unsigned int as1_u32;
typedef __attribute__((address_space(3))) unsigned int as3_u32;
__device__ __forceinline__ void gld16(const short* g, short* l) {
    __builtin_amdgcn_global_load_lds((const as1_u32*)g, (as3_u32*)l, 16, 0, 0);
}

#define RTOK 8
#define CV_CHUNKS 7077888L   // 28311552 elems / 4

// ================================================================ cooperative mega-kernel
__global__ __launch_bounds__(256, 4)
void moe_all(const float* __restrict__ x, const float* __restrict__ rw,
             const float* __restrict__ ebias,
             const float* __restrict__ gw_f, const float* __restrict__ uw_f,
             const float* __restrict__ dw_f, const float* __restrict__ sgw_f,
             const float* __restrict__ suw_f, const float* __restrict__ sdw_f,
             short* __restrict__ g_bf, short* __restrict__ u_bf, short* __restrict__ d_bf,
             short* __restrict__ sg_bf, short* __restrict__ su_bf, short* __restrict__ sd_bf,
             short* __restrict__ xbf,
             int* __restrict__ blk_cnt, int* __restrict__ blk_tok, float* __restrict__ blk_wgt,
             int* __restrict__ counts, int* __restrict__ lists, float* __restrict__ lweights,
             short* __restrict__ h_r, short* __restrict__ h_sh,
             float* __restrict__ out)
{
    cg::grid_group gg = cg::this_grid();
    __shared__ __align__(16) char smem[34816];
    const int bid = blockIdx.x;
    const int tid = threadIdx.x;

    // ================= Phase A: router (blocks 0-255) in parallel with convert (256-1023)
    if (bid < 256) {
        float (*Xs)[H_DIM + 4] = (float (*)[H_DIM + 4])smem;          // 32896 B
        float* part = (float*)(smem + 32896);                          // 1024 B
        float (*lg)[E_EXP] = (float (*)[E_EXP])(smem + 33920);         // 512 B
        int* lcnt = (int*)(smem + 34432);                              // 64 B
        const int t0 = bid * RTOK;
        {
            int r = tid >> 5;
            int cb = (tid & 31) * 4;
            const float* xr = x + (size_t)(t0 + r) * H_DIM;
            short* xw = xbf + (size_t)(t0 + r) * H_DIM;
            #pragma unroll
            for (int j = 0; j < 8; ++j) {
                int c = cb + j * 128;
                float4 v = *(const float4*)(xr + c);
                *(float4*)&Xs[r][c] = v;
                short4 s = { f2bf(v.x), f2bf(v.y), f2bf(v.z), f2bf(v.w) };
                *(short4*)(xw + c) = s;
            }
        }
        __syncthreads();
        {
            int half = tid >> 7;
            int e    = (tid >> 3) & 15;
            int tok  = tid & 7;
            const float* wr  = rw + (size_t)e * H_DIM + half * 512;
            const float* xsr = &Xs[tok][half * 512];
            float acc = 0.f;
            #pragma unroll 4
            for (int k = 0; k < 512; k += 4) {
                float4 w = *(const float4*)(wr + k);
                float4 xv = *(const float4*)(xsr + k);
                acc += w.x * xv.x + w.y * xv.y + w.z * xv.z + w.w * xv.w;
            }
            part[tid] = acc;
        }
        __syncthreads();
        if (tid < 128) {
            float logit = part[tid] + part[tid + 128];
            lg[tid & 7][(tid >> 3) & 15] = logit;
        }
        if (tid < E_EXP) lcnt[tid] = 0;
        __syncthreads();
        if (tid < RTOK) {
            const int t = t0 + tid;
            float scores[E_EXP], sc[E_EXP];
            for (int e = 0; e < E_EXP; ++e) {
                float s = 1.f / (1.f + expf(-lg[tid][e]));
                scores[e] = s;
                sc[e] = s + ebias[e];
            }
            float gs[G_GRP];
            for (int gi = 0; gi < G_GRP; ++gi) {
                float v[4] = { sc[gi*4], sc[gi*4+1], sc[gi*4+2], sc[gi*4+3] };
                float b1 = -1e30f; int i1 = -1;
                for (int j = 0; j < 4; ++j) if (v[j] > b1) { b1 = v[j]; i1 = j; }
                float b2 = -1e30f;
                for (int j = 0; j < 4; ++j) if (j != i1 && v[j] > b2) b2 = v[j];
                gs[gi] = b1 + b2;
            }
            int g1 = -1; float b1 = -1e30f;
            for (int gi = 0; gi < G_GRP; ++gi) if (gs[gi] > b1) { b1 = gs[gi]; g1 = gi; }
            int g2 = -1; float b2 = -1e30f;
            for (int gi = 0; gi < G_GRP; ++gi) if (gi != g1 && gs[gi] > b2) { b2 = gs[gi]; g2 = gi; }

            float masked[E_EXP];
            for (int e = 0; e < E_EXP; ++e) {
                int grp = e >> 2;
                masked[e] = (grp == g1 || grp == g2) ? sc[e] : 0.f;
            }
            int tidx[K_TOP]; float tw[K_TOP];
            for (int k = 0; k < K_TOP; ++k) {
                int bi = -1; float bv = -1e30f;
                for (int e = 0; e < E_EXP; ++e) if (masked[e] > bv) { bv = masked[e]; bi = e; }
                tidx[k] = bi;
                tw[k] = scores[bi];
                masked[bi] = -1e30f;
            }
            float sum = tw[0] + tw[1] + tw[2] + tw[3];
            float inv = SCALE_F / (sum + 1e-20f);
            for (int k = 0; k < K_TOP; ++k) {
                int e = tidx[k];
                int p = atomicAdd(&lcnt[e], 1);          // LDS atomic, block-local
                blk_tok[(bid * E_EXP + e) * 8 + p] = t;
                blk_wgt[(bid * E_EXP + e) * 8 + p] = tw[k] * inv;
            }
        }
        __syncthreads();
        if (tid < E_EXP) blk_cnt[bid * E_EXP + tid] = lcnt[tid];
    } else {
        // ---- convert: partitioned over blocks 256..1023 only (router excluded,
        //      so phase A = max(router, convert) instead of router + share)
        for (long c = ((long)bid - 256) * 256 + tid; c < CV_CHUNKS;
             c += (long)(GRID_C - 256) * 256) {
            long i = c * 4;
            const float* src; short* dst; long off;
            if      (i < 8388608)  { src = gw_f;  dst = g_bf;  off = i; }
            else if (i < 16777216) { src = uw_f;  dst = u_bf;  off = i - 8388608; }
            else if (i < 25165824) { src = dw_f;  dst = d_bf;  off = i - 16777216; }
            else if (i < 26214400) { src = sgw_f; dst = sg_bf; off = i - 25165824; }
            else if (i < 27262976) { src = suw_f; dst = su_bf; off = i - 26214400; }
            else                   { src = sdw_f; dst = sd_bf; off = i - 27262976; }
            float4 v = *(const float4*)(src + off);
            short4 s = { f2bf(v.x), f2bf(v.y), f2bf(v.z), f2bf(v.w) };
            *(short4*)(dst + off) = s;
        }
    }

    gg.sync();

    // ================= Phase B: dense list scan (16 blocks) + zero out (rest)
    if (bid < E_EXP) {
        int* sbuf = (int*)smem;
        const int e = bid;
        int c = blk_cnt[tid * E_EXP + e];
        sbuf[tid] = c;
        __syncthreads();
        for (int off = 1; off < 256; off <<= 1) {
            int v = (tid >= off) ? sbuf[tid - off] : 0;
            __syncthreads();
            sbuf[tid] += v;
            __syncthreads();
        }
        int excl = sbuf[tid] - c;
        for (int j = 0; j < c; ++j) {
            lists[e * T_TOK + excl + j]    = blk_tok[(tid * E_EXP + e) * 8 + j];
            lweights[e * T_TOK + excl + j] = blk_wgt[(tid * E_EXP + e) * 8 + j];
        }
        if (tid == 255) counts[e] = sbuf[255];
    } else {
        float4 zz = {0.f, 0.f, 0.f, 0.f};
        for (int i = (bid - E_EXP) * 256 + tid; i < 524288; i += (GRID_C - E_EXP) * 256)
            *((float4*)out + i) = zz;
    }

    gg.sync();

    const int lane = tid & 63, wv = tid >> 6;
    const int mw = wv & 1, nw = wv >> 1;
    const int lr = lane & 15, lq = lane >> 4;
    const int l3 = lane >> 3, l7 = lane & 7;
    const int seg = (l7 ^ l3) * 8;

    // ================= Phase C: gate+up+silu -> h  (DENSE tile index: no aliasing,
    //  no inactive iterations; round-6 stride-768 aliased mod 256 -> 25% of blocks
    //  did all the work)
    {
        short* sX = (short*)smem;
        short* sG = (short*)(smem + 8192);
        short* sU = (short*)(smem + 16384);
        int* toks = (int*)(smem + 24576);
        // per-expert active-tile prefix (unrolled -> registers; rule #20)
        int prefC[E_EXP + 1];
        prefC[0] = 0;
        #pragma unroll
        for (int e = 0; e < E_EXP; ++e)
            prefC[e + 1] = prefC[e] + (((counts[e] + 63) >> 6) << 3);
        const int totalC = 512 + prefC[E_EXP];

        for (int t = bid; t < totalC; t += GRID_C) {
            const short *gbase, *ubase; short* hout; int hpitch;
            if (t >= 512) {
                int j = t - 512;
                int e = 0, ebase = 0;
                #pragma unroll
                for (int k = 1; k < E_EXP; ++k)
                    if (j >= prefC[k]) { e = k; ebase = prefC[k]; }
                int jj = j - ebase;
                int mt = jj >> 3, nt = jj & 7;
                int cnt = counts[e];
                if (tid < 64) {
                    int jr = mt * 64 + tid;
                    toks[tid] = (jr < cnt) ? lists[e * T_TOK + jr] : lists[e * T_TOK];
                }
                gbase = g_bf + (size_t)e * I_SZ * H_DIM + (size_t)(nt * 64) * H_DIM;
                ubase = u_bf + (size_t)e * I_SZ * H_DIM + (size_t)(nt * 64) * H_DIM;
                hout  = h_r + ((size_t)e * T_TOK + mt * 64) * I_SZ + nt * 64;
                hpitch = I_SZ;
            } else {
                int mt = t >> 4, nt = t & 15;
                if (tid < 64) toks[tid] = mt * 64 + tid;
                gbase = sg_bf + (size_t)(nt * 64) * H_DIM;
                ubase = su_bf + (size_t)(nt * 64) * H_DIM;
                hout  = h_sh + (size_t)(mt * 64) * 1024 + nt * 64;
                hpitch = 1024;
            }
            __syncthreads();

            const int rowA = wv * 16 + l3, rowB = rowA + 8;
            const short* xA = xbf   + (size_t)toks[rowA] * H_DIM + seg;
            const short* xB = xbf   + (size_t)toks[rowB] * H_DIM + seg;
            const short* gA = gbase + (size_t)rowA * H_DIM + seg;
            const short* gB = gbase + (size_t)rowB * H_DIM + seg;
            const short* uA = ubase + (size_t)rowA * H_DIM + seg;
            const short* uB = ubase + (size_t)rowB * H_DIM + seg;
            short* ldsXA = &sX[(wv*16    ) * 64]; short* ldsXB = &sX[(wv*16 + 8) * 64];
            short* ldsGA = &sG[(wv*16    ) * 64]; short* ldsGB = &sG[(wv*16 + 8) * 64];
            short* ldsUA = &sU[(wv*16    ) * 64]; short* ldsUB = &sU[(wv*16 + 8) * 64];

            f32x4 accG[2][2], accU[2][2];
            #pragma unroll
            for (int a = 0; a < 2; ++a)
                #pragma unroll
                for (int b = 0; b < 2; ++b) {
                    accG[a][b] = (f32x4){0.f,0.f,0.f,0.f};
                    accU[a][b] = (f32x4){0.f,0.f,0.f,0.f};
                }

            #pragma unroll
            for (int c = 0; c < 16; ++c) {
                const int kc = c * 64;
                gld16(xA + kc, ldsXA); gld16(xB + kc, ldsXB);
                gld16(gA + kc, ldsGA); gld16(gB + kc, ldsGB);
                gld16(uA + kc, ldsUA); gld16(uB + kc, ldsUB);
                __syncthreads();
                #pragma unroll
                for (int kk = 0; kk < 64; kk += 32) {
                    const int kf = kk + lq * 8;
                    bfrag a0 = *(const bfrag*)&sX[lds_idx(mw*32 + lr,      kf)];
                    bfrag a1 = *(const bfrag*)&sX[lds_idx(mw*32 + 16 + lr, kf)];
                    bfrag g0 = *(const bfrag*)&sG[lds_idx(nw*32 + lr,      kf)];
                    bfrag g1 = *(const bfrag*)&sG[lds_idx(nw*32 + 16 + lr, kf)];
                    bfrag u0 = *(const bfrag*)&sU[lds_idx(nw*32 + lr,      kf)];
                    bfrag u1 = *(const bfrag*)&sU[lds_idx(nw*32 + 16 + lr, kf)];
                    accG[0][0] = MFMA16(a0, g0, accG[0][0]);
                    accG[0][1] = MFMA16(a0, g1, accG[0][1]);
                    accG[1][0] = MFMA16(a1, g0, accG[1][0]);
                    accG[1][1] = MFMA16(a1, g1, accG[1][1]);
                    accU[0][0] = MFMA16(a0, u0, accU[0][0]);
                    accU[0][1] = MFMA16(a0, u1, accU[0][1]);
                    accU[1][0] = MFMA16(a1, u0, accU[1][0]);
                    accU[1][1] = MFMA16(a1, u1, accU[1][1]);
                }
                __syncthreads();
            }

            #pragma unroll
            for (int fm = 0; fm < 2; ++fm)
                #pragma unroll
                for (int fn = 0; fn < 2; ++fn)
                    #pragma unroll
                    for (int r = 0; r < 4; ++r) {
                        int trow = mw*32 + fm*16 + lq*4 + r;
                        int col  = nw*32 + fn*16 + lr;
                        float g = accG[fm][fn][r], u = accU[fm][fn][r];
                        hout[(size_t)trow * hpitch + col] = f2bf(g * u / (1.f + __expf(-g)));
                    }
        }
    }

    gg.sync();

    // ================= Phase D: down-proj (dense tiles, all-atomic onto zeroed out)
    {
        short* Hs = (short*)smem;            // <= 16 KB
        short* Ws = (short*)(smem + 16384);  // <= 16 KB
        int* toks = (int*)(smem + 32768);    // 512 B
        float* tws = (float*)(smem + 33280); // 512 B
        int prefD[E_EXP + 1];
        prefD[0] = 0;
        #pragma unroll
        for (int e = 0; e < E_EXP; ++e)
            prefD[e + 1] = prefD[e] + (((counts[e] + 127) >> 7) << 3);
        const int totalD = 512 + prefD[E_EXP];

        for (int t = bid; t < totalD; t += GRID_C) {
            if (t < 512) {
                // ---- shared expert down: 64x64 tile, K=1024, atomicAdd (w=1)
                const int mt = t >> 4, nt = t & 15;
                const short* abase = h_sh + (size_t)(mt * 64) * 1024;
                const short* bbase = sd_bf + (size_t)(nt * 64) * 1024;

                const int rowA = wv * 16 + l3, rowB = rowA + 8;
                const short* aA = abase + (size_t)rowA * 1024 + seg;
                const short* aB = abase + (size_t)rowB * 1024 + seg;
                const short* bA = bbase + (size_t)rowA * 1024 + seg;
                const short* bB = bbase + (size_t)rowB * 1024 + seg;
                short* lHA = &Hs[(wv*16    ) * 64]; short* lHB = &Hs[(wv*16 + 8) * 64];
                short* lWA = &Ws[(wv*16    ) * 64]; short* lWB = &Ws[(wv*16 + 8) * 64];

                f32x4 acc[2][2];
                #pragma unroll
                for (int m = 0; m < 2; ++m)
                    #pragma unroll
                    for (int n = 0; n < 2; ++n) acc[m][n] = (f32x4){0.f,0.f,0.f,0.f};

                __syncthreads();
                #pragma unroll
                for (int c = 0; c < 16; ++c) {
                    const int kc = c * 64;
                    gld16(aA + kc, lHA); gld16(aB + kc, lHB);
                    gld16(bA + kc, lWA); gld16(bB + kc, lWB);
                    __syncthreads();
                    #pragma unroll
                    for (int kk = 0; kk < 64; kk += 32) {
                        const int kf = kk + lq * 8;
                        bfrag a0 = *(const bfrag*)&Hs[lds_idx(mw*32 +      lr, kf)];
                        bfrag a1 = *(const bfrag*)&Hs[lds_idx(mw*32 + 16 + lr, kf)];
                        bfrag b0 = *(const bfrag*)&Ws[lds_idx(nw*32 +      lr, kf)];
                        bfrag b1 = *(const bfrag*)&Ws[lds_idx(nw*32 + 16 + lr, kf)];
                        acc[0][0] = MFMA16(a0, b0, acc[0][0]); acc[0][1] = MFMA16(a0, b1, acc[0][1]);
                        acc[1][0] = MFMA16(a1, b0, acc[1][0]); acc[1][1] = MFMA16(a1, b1, acc[1][1]);
                    }
                    __syncthreads();
                }

                #pragma unroll
                for (int fm = 0; fm < 2; ++fm)
                    #pragma unroll
                    for (int fn = 0; fn < 2; ++fn)
                        #pragma unroll
                        for (int r = 0; r < 4; ++r) {
                            int trow = mt*64 + mw*32 + fm*16 + lq*4 + r;
                            int col  = nt*64 + nw*32 + fn*16 + lr;
                            atomicAdd(out + (size_t)trow * H_DIM + col, acc[fm][fn][r]);
                        }
            } else {
                // ---- routed down: 128x128 tile, K=512, weighted atomicAdd
                int j = t - 512;
                int e = 0, ebase = 0;
                #pragma unroll
                for (int k = 1; k < E_EXP; ++k)
                    if (j >= prefD[k]) { e = k; ebase = prefD[k]; }
                int jj = j - ebase;
                const int mt = jj >> 3, nt = jj & 7;
                const int cnt = counts[e];
                __syncthreads();   // prior tile's epilogue reads toks/tws from LDS
                if (tid < 128) {
                    int jr = mt * 128 + tid;
                    toks[tid] = (jr < cnt) ? lists[e * T_TOK + jr] : 0;
                    tws[tid]  = (jr < cnt) ? lweights[e * T_TOK + jr] : 0.f;
                }
                const short* abase = h_r + ((size_t)e * T_TOK + mt * 128) * I_SZ;
                const short* bbase = d_bf + (size_t)e * H_DIM * I_SZ + (size_t)(nt * 128) * I_SZ;
                __syncthreads();

                const short* ap[4]; short* al[4];
                const short* bp[4]; short* bl[4];
                #pragma unroll
                for (int s = 0; s < 4; ++s) {
                    int row = wv * 32 + s * 8;
                    ap[s] = abase + (size_t)(row + l3) * I_SZ + seg;
                    al[s] = &Hs[row * 64];
                    bp[s] = bbase + (size_t)(row + l3) * I_SZ + seg;
                    bl[s] = &Ws[row * 64];
                }

                f32x4 acc[4][4];
                #pragma unroll
                for (int m = 0; m < 4; ++m)
                    #pragma unroll
                    for (int n = 0; n < 4; ++n) acc[m][n] = (f32x4){0.f,0.f,0.f,0.f};

                #pragma unroll
                for (int c = 0; c < 8; ++c) {
                    const int kc = c * 64;
                    gld16(ap[0] + kc, al[0]); gld16(ap[1] + kc, al[1]);
                    gld16(ap[2] + kc, al[2]); gld16(ap[3] + kc, al[3]);
                    gld16(bp[0] + kc, bl[0]); gld16(bp[1] + kc, bl[1]);
                    gld16(bp[2] + kc, bl[2]); gld16(bp[3] + kc, bl[3]);
                    __syncthreads();
                    #pragma unroll
                    for (int kk = 0; kk < 64; kk += 32) {
                        const int kf = kk + lq * 8;
                        bfrag a[4], b[4];
                        #pragma unroll
                        for (int m = 0; m < 4; ++m)
                            a[m] = *(const bfrag*)&Hs[lds_idx(mw*64 + m*16 + lr, kf)];
                        #pragma unroll
                        for (int n = 0; n < 4; ++n)
                            b[n] = *(const bfrag*)&Ws[lds_idx(nw*64 + n*16 + lr, kf)];
                        #pragma unroll
                        for (int m = 0; m < 4; ++m)
                            #pragma unroll
                            for (int n = 0; n < 4; ++n)
                                acc[m][n] = MFMA16(a[m], b[n], acc[m][n]);
                    }
                    __syncthreads();
                }

                #pragma unroll
                for (int fm = 0; fm < 4; ++fm) {
                    const int tr0 = mw*64 + fm*16 + lq*4;
                    #pragma unroll
                    for (int r = 0; r < 4; ++r) {
                        float w = tws[tr0 + r];
                        if (w != 0.f) {
                            float* orow = out + (size_t)toks[tr0 + r] * H_DIM + nt*128 + nw*64;
                            #pragma unroll
                            for (int fn = 0; fn < 4; ++fn)
                                atomicAdd(orow + fn*16 + lr, acc[fm][fn][r] * w);
                        }
                    }
                }
            }
        }
    }
}

// ================================================================ round-5 3-dispatch path
// (fallback if cooperative launch is unavailable; verified at 252 us)
__global__ __launch_bounds__(256)
void prep(const float* __restrict__ x, const float* __restrict__ rw,
          const float* __restrict__ ebias,
          const float* __restrict__ g, const float* __restrict__ u, const float* __restrict__ d,
          const float* __restrict__ sg, const float* __restrict__ su, const float* __restrict__ sd,
          short* __restrict__ go, short* __restrict__ uo, short* __restrict__ dd,
          short* __restrict__ sgo, short* __restrict__ suo, short* __restrict__ sdo,
          short* __restrict__ xbf,
          int* __restrict__ blk_cnt, int* __restrict__ blk_tok, float* __restrict__ blk_wgt) {
    const int tid = threadIdx.x;
    if (blockIdx.x >= 256) {
        const long NB = (long)gridDim.x - 256;
        const long step = NB * 256;
        for (long c = ((long)blockIdx.x - 256) * 256 + tid; c < CV_CHUNKS; c += step) {
            long i = c * 4;
            const float* src; short* dst; long off;
            if      (i < 8388608)  { src = g;  dst = go;  off = i; }
            else if (i < 16777216) { src = u;  dst = uo;  off = i - 8388608; }
            else if (i < 25165824) { src = d;  dst = dd;  off = i - 16777216; }
            else if (i < 26214400) { src = sg; dst = sgo; off = i - 25165824; }
            else if (i < 27262976) { src = su; dst = suo; off = i - 26214400; }
            else                   { src = sd; dst = sdo; off = i - 27262976; }
            float4 v = *(const float4*)(src + off);
            short4 s = { f2bf(v.x), f2bf(v.y), f2bf(v.z), f2bf(v.w) };
            *(short4*)(dst + off) = s;
        }
        return;
    }
    __shared__ float Xs[RTOK][H_DIM + 4];
    __shared__ float part[256];
    __shared__ float lg[RTOK][E_EXP];
    __shared__ int lcnt[E_EXP];
    const int b = blockIdx.x;
    const int t0 = b * RTOK;
    {
        int r = tid >> 5;
        int cb = (tid & 31) * 4;
        const float* xr = x + (size_t)(t0 + r) * H_DIM;
        short* xw = xbf + (size_t)(t0 + r) * H_DIM;
        #pragma unroll
        for (int j = 0; j < 8; ++j) {
            int c = cb + j * 128;
            float4 v = *(const float4*)(xr + c);
            *(float4*)&Xs[r][c] = v;
            short4 s = { f2bf(v.x), f2bf(v.y), f2bf(v.z), f2bf(v.w) };
            *(short4*)(xw + c) = s;
        }
    }
    __syncthreads();
    {
        int half = tid >> 7;
        int e    = (tid >> 3) & 15;
        int tok  = tid & 7;
        const float* wr  = rw + (size_t)e * H_DIM + half * 512;
        const float* xsr = &Xs[tok][half * 512];
        float acc = 0.f;
        #pragma unroll 4
        for (int k = 0; k < 512; k += 4) {
            float4 w = *(const float4*)(wr + k);
            float4 xv = *(const float4*)(xsr + k);
            acc += w.x * xv.x + w.y * xv.y + w.z * xv.z + w.w * xv.w;
        }
        part[tid] = acc;
    }
    __syncthreads();
    if (tid < 128) {
        float logit = part[tid] + part[tid + 128];
        lg[tid & 7][(tid >> 3) & 15] = logit;
    }
    if (tid < E_EXP) lcnt[tid] = 0;
    __syncthreads();
    if (tid < RTOK) {
        const int t = t0 + tid;
        float scores[E_EXP], sc[E_EXP];
        for (int e = 0; e < E_EXP; ++e) {
            float s = 1.f / (1.f + expf(-lg[tid][e]));
            scores[e] = s;
            sc[e] = s + ebias[e];
        }
        float gs[G_GRP];
        for (int gi = 0; gi < G_GRP; ++gi) {
            float v[4] = { sc[gi*4], sc[gi*4+1], sc[gi*4+2], sc[gi*4+3] };
            float b1 = -1e30f; int i1 = -1;
            for (int j = 0; j < 4; ++j) if (v[j] > b1) { b1 = v[j]; i1 = j; }
            float b2 = -1e30f;
            for (int j = 0; j < 4; ++j) if (j != i1 && v[j] > b2) b2 = v[j];
            gs[gi] = b1 + b2;
        }
        int g1 = -1; float b1 = -1e30f;
        for (int gi = 0; gi < G_GRP; ++gi) if (gs[gi] > b1) { b1 = gs[gi]; g1 = gi; }
        int g2 = -1; float b2 = -1e30f;
        for (int gi = 0; gi < G_GRP; ++gi) if (gi != g1 && gs[gi] > b2) { b2 = gs[gi]; g2 = gi; }
        float masked[E_EXP];
        for (int e = 0; e < E_EXP; ++e) {
            int grp = e >> 2;
            masked[e] = (grp == g1 || grp == g2) ? sc[e] : 0.f;
        }
        int tidx[K_TOP]; float tw[K_TOP];
        for (int k = 0; k < K_TOP; ++k) {
            int bi = -1; float bv = -1e30f;
            for (int e = 0; e < E_EXP; ++e) if (masked[e] > bv) { bv = masked[e]; bi = e; }
            tidx[k] = bi;
            tw[k] = scores[bi];
            masked[bi] = -1e30f;
        }
        float sum = tw[0] + tw[1] + tw[2] + tw[3];
        float inv = SCALE_F / (sum + 1e-20f);
        for (int k = 0; k < K_TOP; ++k) {
            int e = tidx[k];
            int p = atomicAdd(&lcnt[e], 1);
            blk_tok[(b * E_EXP + e) * 8 + p] = t;
            blk_wgt[(b * E_EXP + e) * 8 + p] = tw[k] * inv;
        }
    }
    __syncthreads();
    if (tid < E_EXP) blk_cnt[b * E_EXP + tid] = lcnt[tid];
}

__global__ __launch_bounds__(256)
void moe_gateup(const short* __restrict__ Xbf,
                const int* __restrict__ blk_cnt, const int* __restrict__ blk_tok,
                const short* __restrict__ gw, const short* __restrict__ uw,
                const short* __restrict__ sgw, const short* __restrict__ suw,
                short* __restrict__ h_r, short* __restrict__ h_sh,
                float* __restrict__ out) {
    const int bx = blockIdx.x, tid = threadIdx.x;
    if (bx >= 4608) {
        int z = bx - 4608;
        float4 zz = {0.f, 0.f, 0.f, 0.f};
        float4* o4 = (float4*)out + (size_t)z * 1024;
        #pragma unroll
        for (int i = 0; i < 4; ++i) o4[i * 256 + tid] = zz;
        return;
    }
    __shared__ __align__(16) short Xs[64*64], Gs[64*64], Us[64*64];
    __shared__ int toks[64];
    __shared__ int sbuf[256];
    const short *gbase, *ubase; short* hout; int hpitch;
    if (bx >= 512) {
        int b2 = bx - 512;
        int e = b2 >> 8, mt = (b2 >> 3) & 31, nt = b2 & 7;
        int c = blk_cnt[tid * E_EXP + e];
        sbuf[tid] = c;
        if (tid < 64) toks[tid] = 0;
        __syncthreads();
        for (int off = 1; off < 256; off <<= 1) {
            int v = (tid >= off) ? sbuf[tid - off] : 0;
            __syncthreads();
            sbuf[tid] += v;
            __syncthreads();
        }
        int cnt = sbuf[255];
        if (mt * 64 >= cnt) return;
        int excl = sbuf[tid] - c;
        int lo = mt * 64;
        for (int j = 0; j < c; ++j) {
            int r = excl + j - lo;
            if (r >= 0 && r < 64) toks[r] = blk_tok[(tid * E_EXP + e) * 8 + j];
        }
        gbase = gw + (size_t)e * I_SZ * H_DIM + (size_t)(nt * 64) * H_DIM;
        ubase = uw + (size_t)e * I_SZ * H_DIM + (size_t)(nt * 64) * H_DIM;
        hout  = h_r + ((size_t)e * T_TOK + mt * 64) * I_SZ + nt * 64;
        hpitch = I_SZ;
    } else {
        int mt = bx >> 4, nt = bx & 15;
        if (tid < 64) toks[tid] = mt * 64 + tid;
        gbase = sgw + (size_t)(nt * 64) * H_DIM;
        ubase = suw + (size_t)(nt * 64) * H_DIM;
        hout  = h_sh + (size_t)(mt * 64) * 1024 + nt * 64;
        hpitch = 1024;
    }
    __syncthreads();

    const int lane = tid & 63, wv = tid >> 6;
    const int mw = wv & 1, nw = wv >> 1;
    const int lr = lane & 15, lq = lane >> 4;
    const int l3 = lane >> 3, l7 = lane & 7;
    const int seg = (l7 ^ l3) * 8;

    const int rowA = wv * 16 + l3, rowB = rowA + 8;
    const short* xA = Xbf   + (size_t)toks[rowA] * H_DIM + seg;
    const short* xB = Xbf   + (size_t)toks[rowB] * H_DIM + seg;
    const short* gA = gbase + (size_t)rowA * H_DIM + seg;
    const short* gB = gbase + (size_t)rowB * H_DIM + seg;
    const short* uA = ubase + (size_t)rowA * H_DIM + seg;
    const short* uB = ubase + (size_t)rowB * H_DIM + seg;
    short* ldsXA = &Xs[(wv*16    ) * 64]; short* ldsXB = &Xs[(wv*16 + 8) * 64];
    short* ldsGA = &Gs[(wv*16    ) * 64]; short* ldsGB = &Gs[(wv*16 + 8) * 64];
    short* ldsUA = &Us[(wv*16    ) * 64]; short* ldsUB = &Us[(wv*16 + 8) * 64];

    f32x4 accG[2][2], accU[2][2];
    #pragma unroll
    for (int a = 0; a < 2; ++a)
        #pragma unroll
        for (int b = 0; b < 2; ++b) {
            accG[a][b] = (f32x4){0.f,0.f,0.f,0.f};
            accU[a][b] = (f32x4){0.f,0.f,0.f,0.f};
        }

    #pragma unroll
    for (int c = 0; c < 16; ++c) {
        const int kc = c * 64;
        gld16(xA + kc, ldsXA); gld16(xB + kc, ldsXB);
        gld16(gA + kc, ldsGA); gld16(gB + kc, ldsGB);
        gld16(uA + kc, ldsUA); gld16(uB + kc, ldsUB);
        __syncthreads();
        #pragma unroll
        for (int kk = 0; kk < 64; kk += 32) {
            const int kf = kk + lq * 8;
            bfrag a0 = *(const bfrag*)&Xs[lds_idx(mw*32 + lr,      kf)];
            bfrag a1 = *(const bfrag*)&Xs[lds_idx(mw*32 + 16 + lr, kf)];
            bfrag g0 = *(const bfrag*)&Gs[lds_idx(nw*32 + lr,      kf)];
            bfrag g1 = *(const bfrag*)&Gs[lds_idx(nw*32 + 16 + lr, kf)];
            bfrag u0 = *(const bfrag*)&Us[lds_idx(nw*32 + lr,      kf)];
            bfrag u1 = *(const bfrag*)&Us[lds_idx(nw*32 + 16 + lr, kf)];
            accG[0][0] = MFMA16(a0, g0, accG[0][0]);
            accG[0][1] = MFMA16(a0, g1, accG[0][1]);
            accG[1][0] = MFMA16(a1, g0, accG[1][0]);
            accG[1][1] = MFMA16(a1, g1, accG[1][1]);
            accU[0][0] = MFMA16(a0, u0, accU[0][0]);
            accU[0][1] = MFMA16(a0, u1, accU[0][1]);
            accU[1][0] = MFMA16(a1, u0, accU[1][0]);
            accU[1][1] = MFMA16(a1, u1, accU[1][1]);
        }
        __syncthreads();
    }

    #pragma unroll
    for (int fm = 0; fm < 2; ++fm)
        #pragma unroll
        for (int fn = 0; fn < 2; ++fn)
            #pragma unroll
            for (int r = 0; r < 4; ++r) {
                int trow = mw*32 + fm*16 + lq*4 + r;
                int col  = nw*32 + fn*16 + lr;
                float g = accG[fm][fn][r], u = accU[fm][fn][r];
                hout[(size_t)trow * hpitch + col] = f2bf(g * u / (1.f + __expf(-g)));
            }
}

__global__ __launch_bounds__(256)
void moe_down(const short* __restrict__ h_r, const short* __restrict__ h_sh,
              const int* __restrict__ blk_cnt, const int* __restrict__ blk_tok,
              const float* __restrict__ blk_wgt,
              const short* __restrict__ dw, const short* __restrict__ shdw,
              float* __restrict__ out) {
    __shared__ __align__(16) short Hs[128*64], Ws[128*64];
    __shared__ int toks[128];
    __shared__ float tws[128];
    __shared__ int sbuf[256];
    const int bx = blockIdx.x, tid = threadIdx.x;
    const int lane = tid & 63, wv = tid >> 6;
    const int mw = wv & 1, nw = wv >> 1;
    const int lr = lane & 15, lq = lane >> 4;
    const int l3 = lane >> 3, l7 = lane & 7;
    const int seg = (l7 ^ l3) * 8;

    if (bx < 512) {
        const int mt = bx >> 4, nt = bx & 15;
        const short* abase = h_sh + (size_t)(mt * 64) * 1024;
        const short* bbase = shdw + (size_t)(nt * 64) * 1024;
        const int rowA = wv * 16 + l3, rowB = rowA + 8;
        const short* aA = abase + (size_t)rowA * 1024 + seg;
        const short* aB = abase + (size_t)rowB * 1024 + seg;
        const short* bA = bbase + (size_t)rowA * 1024 + seg;
        const short* bB = bbase + (size_t)rowB * 1024 + seg;
        short* lHA = &Hs[(wv*16    ) * 64]; short* lHB = &Hs[(wv*16 + 8) * 64];
        short* lWA = &Ws[(wv*16    ) * 64]; short* lWB = &Ws[(wv*16 + 8) * 64];
        f32x4 acc[2][2];
        #pragma unroll
        for (int m = 0; m < 2; ++m)
            #pragma unroll
            for (int n = 0; n < 2; ++n) acc[m][n] = (f32x4){0.f,0.f,0.f,0.f};
        #pragma unroll
        for (int c = 0; c < 16; ++c) {
            const int kc = c * 64;
            gld16(aA + kc, lHA); gld16(aB + kc, lHB);
            gld16(bA + kc, lWA); gld16(bB + kc, lWB);
            __syncthreads();
            #pragma unroll
            for (int kk = 0; kk < 64; kk += 32) {
                const int kf = kk + lq * 8;
                bfrag a0 = *(const bfrag*)&Hs[lds_idx(mw*32 +      lr, kf)];
                bfrag a1 = *(const bfrag*)&Hs[lds_idx(mw*32 + 16 + lr, kf)];
                bfrag b0 = *(const bfrag*)&Ws[lds_idx(nw*32 +      lr, kf)];
                bfrag b1 = *(const bfrag*)&Ws[lds_idx(nw*32 + 16 + lr, kf)];
                acc[0][0] = MFMA16(a0, b0, acc[0][0]); acc[0][1] = MFMA16(a0, b1, acc[0][1]);
                acc[1][0] = MFMA16(a1, b0, acc[1][0]); acc[1][1] = MFMA16(a1, b1, acc[1][1]);
            }
            __syncthreads();
        }
        #pragma unroll
        for (int fm = 0; fm < 2; ++fm)
            #pragma unroll
            for (int fn = 0; fn < 2; ++fn)
                #pragma unroll
                for (int r = 0; r < 4; ++r) {
                    int trow = mt*64 + mw*32 + fm*16 + lq*4 + r;
                    int col  = nt*64 + nw*32 + fn*16 + lr;
                    atomicAdd(out + (size_t)trow * H_DIM + col, acc[fm][fn][r]);
                }
        return;
    }

    const int b2 = bx - 512;
    const int e = b2 >> 7, mt = (b2 >> 3) & 15, nt = b2 & 7;
    {
        int c = blk_cnt[tid * E_EXP + e];
        sbuf[tid] = c;
        if (tid < 128) { toks[tid] = 0; tws[tid] = 0.f; }
        __syncthreads();
        for (int off = 1; off < 256; off <<= 1) {
            int v = (tid >= off) ? sbuf[tid - off] : 0;
            __syncthreads();
            sbuf[tid] += v;
            __syncthreads();
        }
        int cnt = sbuf[255];
        if (mt * 128 >= cnt) return;
        int excl = sbuf[tid] - c;
        int lo = mt * 128;
        for (int j = 0; j < c; ++j) {
            int r = excl + j - lo;
            if (r >= 0 && r < 128) {
                toks[r] = blk_tok[(tid * E_EXP + e) * 8 + j];
                tws[r]  = blk_wgt[(tid * E_EXP + e) * 8 + j];
            }
        }
    }
    const short* abase = h_r + ((size_t)e * T_TOK + mt * 128) * I_SZ;
    const short* bbase = dw + (size_t)e * H_DIM * I_SZ + (size_t)(nt * 128) * I_SZ;
    __syncthreads();

    const short* ap[4]; short* al[4];
    const short* bp[4]; short* bl[4];
    #pragma unroll
    for (int s = 0; s < 4; ++s) {
        int row = wv * 32 + s * 8;
        ap[s] = abase + (size_t)(row + l3) * I_SZ + seg;
        al[s] = &Hs[row * 64];
        bp[s] = bbase + (size_t)(row + l3) * I_SZ + seg;
        bl[s] = &Ws[row * 64];
    }
    f32x4 acc[4][4];
    #pragma unroll
    for (int m = 0; m < 4; ++m)
        #pragma unroll
        for (int n = 0; n < 4; ++n) acc[m][n] = (f32x4){0.f,0.f,0.f,0.f};
    #pragma unroll
    for (int c = 0; c < 8; ++c) {
        const int kc = c * 64;
        gld16(ap[0] + kc, al[0]); gld16(ap[1] + kc, al[1]);
        gld16(ap[2] + kc, al[2]); gld16(ap[3] + kc, al[3]);
        gld16(bp[0] + kc, bl[0]); gld16(bp[1] + kc, bl[1]);
        gld16(bp[2] + kc, bl[2]); gld16(bp[3] + kc, bl[3]);
        __syncthreads();
        #pragma unroll
        for (int kk = 0; kk < 64; kk += 32) {
            const int kf = kk + lq * 8;
            bfrag a[4], b[4];
            #pragma unroll
            for (int m = 0; m < 4; ++m)
                a[m] = *(const bfrag*)&Hs[lds_idx(mw*64 + m*16 + lr, kf)];
            #pragma unroll
            for (int n = 0; n < 4; ++n)
                b[n] = *(const bfrag*)&Ws[lds_idx(nw*64 + n*16 + lr, kf)];
            #pragma unroll
            for (int m = 0; m < 4; ++m)
                #pragma unroll
                for (int n = 0; n < 4; ++n)
                    acc[m][n] = MFMA16(a[m], b[n], acc[m][n]);
        }
        __syncthreads();
    }
    #pragma unroll
    for (int fm = 0; fm < 4; ++fm) {
        const int tr0 = mw*64 + fm*16 + lq*4;
        #pragma unroll
        for (int r = 0; r < 4; ++r) {
            float w = tws[tr0 + r];
            if (w != 0.f) {
                float* orow = out + (size_t)toks[tr0 + r] * H_DIM + nt*128 + nw*64;
                #pragma unroll
                for (int fn = 0; fn < 4; ++fn)
                    atomicAdd(orow + fn*16 + lr, acc[fm][fn][r] * w);
            }
        }
    }
}

// ---------------------------------------------------------------- fp32 fallback (small ws)
__global__ void zero_kernel(float* __restrict__ out, int n4, int* __restrict__ counts) {
    int i = blockIdx.x * blockDim.x + threadIdx.x;
    if (i < n4) {
        float4 z = {0.f, 0.f, 0.f, 0.f};
        *(float4*)(out + (size_t)i * 4) = z;
    }
    if (blockIdx.x == 0 && threadIdx.x < E_EXP) counts[threadIdx.x] = 0;
}

__global__ __launch_bounds__(256)
void router_legacy(const float* __restrict__ x, const float* __restrict__ rw,
                   const float* __restrict__ ebias, int* __restrict__ counts,
                   int* __restrict__ lists, float* __restrict__ lweights) {
    __shared__ float Xs[RTOK][H_DIM + 4];
    __shared__ float part[256];
    __shared__ float lg[RTOK][E_EXP];
    const int tid = threadIdx.x;
    const int t0 = blockIdx.x * RTOK;
    {
        int r = tid >> 5;
        int cb = (tid & 31) * 4;
        const float* xr = x + (size_t)(t0 + r) * H_DIM;
        #pragma unroll
        for (int j = 0; j < 8; ++j) {
            int c = cb + j * 128;
            *(float4*)&Xs[r][c] = *(const float4*)(xr + c);
        }
    }
    __syncthreads();
    {
        int half = tid >> 7;
        int e    = (tid >> 3) & 15;
        int tok  = tid & 7;
        const float* wr  = rw + (size_t)e * H_DIM + half * 512;
        const float* xsr = &Xs[tok][half * 512];
        float acc = 0.f;
        #pragma unroll 4
        for (int k = 0; k < 512; k += 4) {
            float4 w = *(const float4*)(wr + k);
            float4 xv = *(const float4*)(xsr + k);
            acc += w.x * xv.x + w.y * xv.y + w.z * xv.z + w.w * xv.w;
        }
        part[tid] = acc;
    }
    __syncthreads();
    if (tid < 128) {
        float logit = part[tid] + part[tid + 128];
        lg[tid & 7][(tid >> 3) & 15] = logit;
    }
    __syncthreads();
    if (tid >= RTOK) return;
    const int t = t0 + tid;
    float scores[E_EXP], sc[E_EXP];
    for (int e = 0; e < E_EXP; ++e) {
        float s = 1.f / (1.f + expf(-lg[tid][e]));
        scores[e] = s;
        sc[e] = s + ebias[e];
    }
    float gs[G_GRP];
    for (int g = 0; g < G_GRP; ++g) {
        float v[4] = { sc[g*4], sc[g*4+1], sc[g*4+2], sc[g*4+3] };
        float b1 = -1e30f; int i1 = -1;
        for (int j = 0; j < 4; ++j) if (v[j] > b1) { b1 = v[j]; i1 = j; }
        float b2 = -1e30f;
        for (int j = 0; j < 4; ++j) if (j != i1 && v[j] > b2) b2 = v[j];
        gs[g] = b1 + b2;
    }
    int g1 = -1; float b1 = -1e30f;
    for (int g = 0; g < G_GRP; ++g) if (gs[g] > b1) { b1 = gs[g]; g1 = g; }
    int g2 = -1; float b2 = -1e30f;
    for (int g = 0; g < G_GRP; ++g) if (g != g1 && gs[g] > b2) { b2 = gs[g]; g2 = g; }
    float masked[E_EXP];
    for (int e = 0; e < E_EXP; ++e) {
        int grp = e >> 2;
        masked[e] = (grp == g1 || grp == g2) ? sc[e] : 0.f;
    }
    int tidx[K_TOP]; float tw[K_TOP];
    for (int k = 0; k < K_TOP; ++k) {
        int bi = -1; float bv = -1e30f;
        for (int e = 0; e < E_EXP; ++e) if (masked[e] > bv) { bv = masked[e]; bi = e; }
        tidx[k] = bi;
        tw[k] = scores[bi];
        masked[bi] = -1e30f;
    }
    float sum = tw[0] + tw[1] + tw[2] + tw[3];
    float inv = SCALE_F / (sum + 1e-20f);
    for (int k = 0; k < K_TOP; ++k) {
        int e = tidx[k];
        int pos = atomicAdd(&counts[e], 1);
        lists[e * T_TOK + pos] = t;
        lweights[e * T_TOK + pos] = tw[k] * inv;
    }
}

__device__ __forceinline__ bfrag load_wfrag_f(const float* p) {
    float4 a = *(const float4*)(p);
    float4 b = *(const float4*)(p + 4);
    bfrag r;
    r[0]=f2bf(a.x); r[1]=f2bf(a.y); r[2]=f2bf(a.z); r[3]=f2bf(a.w);
    r[4]=f2bf(b.x); r[5]=f2bf(b.y); r[6]=f2bf(b.z); r[7]=f2bf(b.w);
    return r;
}

#define TM 32
__global__ __launch_bounds__(256)
void moe_gemm_fb(const float* __restrict__ x,
                 const float* __restrict__ gate_w, const float* __restrict__ up_w,
                 const float* __restrict__ down_w, const float* __restrict__ sh_gate,
                 const float* __restrict__ sh_up, const float* __restrict__ sh_down,
                 const int* __restrict__ counts, const int* __restrict__ lists,
                 const float* __restrict__ lweights, float* __restrict__ out) {
    const int bx = blockIdx.x;
    const int e = bx >> 6;
    const int tile = bx & 63;
    int ntok; const float *gp, *upp, *dpp; int dpitch;
    if (e < E_EXP) {
        ntok = counts[e];
        gp  = gate_w + (size_t)e * I_SZ * H_DIM;
        upp = up_w   + (size_t)e * I_SZ * H_DIM;
        dpp = down_w + (size_t)e * H_DIM * I_SZ;
        dpitch = I_SZ;
    } else {
        int s = e - E_EXP;
        ntok = T_TOK;
        gp  = sh_gate + (size_t)s * I_SZ * H_DIM;
        upp = sh_up   + (size_t)s * I_SZ * H_DIM;
        dpp = sh_down + (size_t)s * I_SZ;
        dpitch = 2 * I_SZ;
    }
    const int start = tile * TM;
    if (start >= ntok) return;

    __shared__ __align__(16) short Xs2[TM][H_DIM + 8];
    __shared__ __align__(16) short Hs2[TM][I_SZ + 8];
    __shared__ int   toks[TM];
    __shared__ float tws[TM];

    const int tid = threadIdx.x;
    if (tid < TM) {
        int j = start + tid;
        int tok = 0; float w = 0.f;
        if (j < ntok) {
            if (e < E_EXP) { tok = lists[e * T_TOK + j]; w = lweights[e * T_TOK + j]; }
            else           { tok = j;                    w = 1.0f; }
        }
        toks[tid] = tok; tws[tid] = w;
    }
    __syncthreads();
    {
        int r = tid >> 3;
        int c0 = (tid & 7) * 128;
        const float* xr = x + (size_t)toks[r] * H_DIM + c0;
        #pragma unroll
        for (int c = 0; c < 128; c += 4) {
            float4 v = *(const float4*)(xr + c);
            short4 s = { f2bf(v.x), f2bf(v.y), f2bf(v.z), f2bf(v.w) };
            *(short4*)&Xs2[r][c0 + c] = s;
        }
    }
    __syncthreads();

    const int lane = tid & 63;
    const int wv   = tid >> 6;
    const int lr   = lane & 15;
    const int lq   = lane >> 4;
    const int ko   = lq * 8;

    for (int it = 0; it < I_SZ / 64; ++it) {
        const int i0 = wv * (I_SZ / 4) + it * 16;
        const float* grow = gp  + (size_t)(i0 + lr) * H_DIM;
        const float* urow = upp + (size_t)(i0 + lr) * H_DIM;
        f32x4 aG0 = {0.f,0.f,0.f,0.f}, aU0 = {0.f,0.f,0.f,0.f};
        f32x4 aG1 = {0.f,0.f,0.f,0.f}, aU1 = {0.f,0.f,0.f,0.f};
        for (int k0 = 0; k0 < H_DIM; k0 += 32) {
            bfrag bg = load_wfrag_f(grow + k0 + ko);
            bfrag bu = load_wfrag_f(urow + k0 + ko);
            bfrag a0 = *(const bfrag*)&Xs2[lr][k0 + ko];
            bfrag a1 = *(const bfrag*)&Xs2[lr + 16][k0 + ko];
            aG0 = MFMA16(a0, bg, aG0);
            aG1 = MFMA16(a1, bg, aG1);
            aU0 = MFMA16(a0, bu, aU0);
            aU1 = MFMA16(a1, bu, aU1);
        }
        #pragma unroll
        for (int r = 0; r < 4; ++r) {
            const int trow = lq * 4 + r;
            float g0 = aG0[r], u0 = aU0[r];
            Hs2[trow][i0 + lr] = f2bf(g0 * u0 / (1.f + __expf(-g0)));
            float g1 = aG1[r], u1 = aU1[r];
            Hs2[trow + 16][i0 + lr] = f2bf(g1 * u1 / (1.f + __expf(-g1)));
        }
    }
    __syncthreads();

    for (int ct = 0; ct < H_DIM / 64; ++ct) {
        const int c0 = wv * (H_DIM / 4) + ct * 16;
        const float* drow = dpp + (size_t)(c0 + lr) * dpitch;
        f32x4 a0 = {0.f,0.f,0.f,0.f}, a1 = {0.f,0.f,0.f,0.f};
        for (int k0 = 0; k0 < I_SZ; k0 += 32) {
            bfrag bd = load_wfrag_f(drow + k0 + ko);
            bfrag h0 = *(const bfrag*)&Hs2[lr][k0 + ko];
            bfrag h1 = *(const bfrag*)&Hs2[lr + 16][k0 + ko];
            a0 = MFMA16(h0, bd, a0);
            a1 = MFMA16(h1, bd, a1);
        }
        #pragma unroll
        for (int r = 0; r < 4; ++r) {
            const int trow = lq * 4 + r;
            float w0 = tws[trow], w1 = tws[trow + 16];
            if (w0 != 0.f) atomicAdd(out + (size_t)toks[trow] * H_DIM + c0 + lr, a0[r] * w0);
            if (w1 != 0.f) atomicAdd(out + (size_t)toks[trow + 16] * H_DIM + c0 + lr, a1[r] * w1);
        }
    }
}

// ---------------------------------------------------------------- launch
extern "C" void kernel_launch(void* const* d_in, const int* in_sizes, int n_in,
                              void* d_out, int out_size, void* d_ws, size_t ws_size,
                              hipStream_t stream) {
    const float* x     = (const float*)d_in[0];
    const float* rw    = (const float*)d_in[1];
    const float* ebias = (const float*)d_in[2];
    const float* gate_w = (const float*)d_in[3];
    const float* up_w   = (const float*)d_in[4];
    const float* down_w = (const float*)d_in[5];
    const float* shg    = (const float*)d_in[6];
    const float* shu    = (const float*)d_in[7];
    const float* shd    = (const float*)d_in[8];
    float* out = (float*)d_out;

    char* ws = (char*)d_ws;
    int*   blk_cnt = (int*)ws;                        // 16 KB
    int*   blk_tok = (int*)(ws + 16384);              // 128 KB
    float* blk_wgt = (float*)(ws + 16384 + 131072);   // 128 KB
    int*   counts  = (int*)(ws + 278528);             // 1 KB
    int*   lists   = (int*)(ws + 279552);             // 128 KB
    float* lw      = (float*)(ws + 279552 + 131072);  // 128 KB
    size_t off = 279552 + 131072 + 131072;            // 541696

    const size_t n_gu = (size_t)E_EXP * I_SZ * H_DIM;   // 8388608
    const size_t n_sh = (size_t)H_DIM * 1024;           // 1048576
    const size_t n_x  = (size_t)T_TOK * H_DIM;          // 2097152

    short* g_bf  = (short*)(ws + off); off += n_gu * 2;
    short* u_bf  = (short*)(ws + off); off += n_gu * 2;
    short* d_bf  = (short*)(ws + off); off += n_gu * 2;
    short* sg_bf = (short*)(ws + off); off += n_sh * 2;
    short* su_bf = (short*)(ws + off); off += n_sh * 2;
    short* sd_bf = (short*)(ws + off); off += n_sh * 2;
    short* x_bf  = (short*)(ws + off); off += n_x * 2;
    short* h_r   = (short*)(ws + off); off += (size_t)E_EXP * T_TOK * I_SZ * 2;  // 32 MB
    short* h_sh  = (short*)(ws + off); off += (size_t)T_TOK * 1024 * 2;          // 4 MB
    const size_t need = off;

    if (ws_size >= need) {
        void* kargs[] = { (void*)&x, (void*)&rw, (void*)&ebias,
                          (void*)&gate_w, (void*)&up_w, (void*)&down_w,
                          (void*)&shg, (void*)&shu, (void*)&shd,
                          (void*)&g_bf, (void*)&u_bf, (void*)&d_bf,
                          (void*)&sg_bf, (void*)&su_bf, (void*)&sd_bf,
                          (void*)&x_bf,
                          (void*)&blk_cnt, (void*)&blk_tok, (void*)&blk_wgt,
                          (void*)&counts, (void*)&lists, (void*)&lw,
                          (void*)&h_r, (void*)&h_sh, (void*)&out };
        hipError_t err = hipLaunchCooperativeKernel((const void*)moe_all,
                                                    dim3(GRID_C), dim3(256),
                                                    kargs, 0, stream);
        if (err != hipSuccess) {
            (void)hipGetLastError();   // clear sticky error, fall back to 3-dispatch path
            prep<<<256 + 3456, 256, 0, stream>>>(x, rw, ebias,
                                                 gate_w, up_w, down_w, shg, shu, shd,
                                                 g_bf, u_bf, d_bf, sg_bf, su_bf, sd_bf,
                                                 x_bf, blk_cnt, blk_tok, blk_wgt);
            moe_gateup<<<512 + 4096 + 512, 256, 0, stream>>>(x_bf, blk_cnt, blk_tok,
                                                             g_bf, u_bf, sg_bf, su_bf,
                                                             h_r, h_sh, out);
            moe_down<<<512 + 2048, 256, 0, stream>>>(h_r, h_sh, blk_cnt, blk_tok, blk_wgt,
                                                     d_bf, sd_bf, out);
        }
    } else {
        zero_kernel<<<(out_size / 4 + 255) / 256, 256, 0, stream>>>(out, out_size / 4, counts);
        router_legacy<<<T_TOK / RTOK, 256, 0, stream>>>(x, rw, ebias, counts, lists, lw);
        moe_gemm_fb<<<(E_EXP + 2) * 64, 256, 0, stream>>>(x, gate_w, up_w, down_w,
                                                          shg, shu, shd, counts, lists, lw, out);
    }
}

// Round 8
// 247.091 us; speedup vs baseline: 2.6353x; 2.6353x over previous
//
#include <hip/hip_runtime.h>
#include <hip/hip_bf16.h>
#include <math.h>

// Problem constants (DeepseekV3MoE reference)
#define T_TOK 2048
#define H_DIM 1024
#define E_EXP 16
#define K_TOP 4
#define G_GRP 4
#define I_SZ 512
#define SCALE_F 2.5f

typedef __attribute__((ext_vector_type(8))) short bfrag;    // 8 bf16 (4 VGPR)
typedef __attribute__((ext_vector_type(4))) float f32x4;    // MFMA acc

#define MFMA16(a, b, c) __builtin_amdgcn_mfma_f32_16x16x32_bf16(a, b, c, 0, 0, 0)

__device__ __forceinline__ short f2bf(float f) {
    union { float f; unsigned u; } v; v.f = f;
    unsigned u = v.u;
    u += 0x7fffu + ((u >> 16) & 1u);   // RNE
    return (short)(u >> 16);
}

// XOR-swizzled LDS index for 64-short rows (verified conflict-free).
__device__ __forceinline__ int lds_idx(int row, int k) {
    return row * 64 + ((((k >> 3) ^ (row & 7))) << 3) + (k & 7);
}

typedef __attribute__((address_space(1))) unsigned int as1_u32;
typedef __attribute__((address_space(3))) unsigned int as3_u32;
__device__ __forceinline__ void gld16(const short* g, short* l) {
    __builtin_amdgcn_global_load_lds((const as1_u32*)g, (as3_u32*)l, 16, 0, 0);
}

#define RTOK 8
#define CV_CHUNKS 7077888L   // 28311552 elems / 4

// ================================================================ Dispatch 1: prep
// blocks 0..255: router (atomic-free: per-block dense expert lists, no init needed)
// blocks 256+ : fp32->bf16 conversion of all weights (grid-stride, unit-stride)
__global__ __launch_bounds__(256)
void prep(const float* __restrict__ x, const float* __restrict__ rw,
          const float* __restrict__ ebias,
          const float* __restrict__ g, const float* __restrict__ u, const float* __restrict__ d,
          const float* __restrict__ sg, const float* __restrict__ su, const float* __restrict__ sd,
          short* __restrict__ go, short* __restrict__ uo, short* __restrict__ dd,
          short* __restrict__ sgo, short* __restrict__ suo, short* __restrict__ sdo,
          short* __restrict__ xbf,
          int* __restrict__ blk_cnt, int* __restrict__ blk_tok, float* __restrict__ blk_wgt) {
    const int tid = threadIdx.x;
    if (blockIdx.x >= 256) {
        const long NB = (long)gridDim.x - 256;
        const long step = NB * 256;
        for (long c = ((long)blockIdx.x - 256) * 256 + tid; c < CV_CHUNKS; c += step) {
            long i = c * 4;
            const float* src; short* dst; long off;
            if      (i < 8388608)  { src = g;  dst = go;  off = i; }
            else if (i < 16777216) { src = u;  dst = uo;  off = i - 8388608; }
            else if (i < 25165824) { src = d;  dst = dd;  off = i - 16777216; }
            else if (i < 26214400) { src = sg; dst = sgo; off = i - 25165824; }
            else if (i < 27262976) { src = su; dst = suo; off = i - 26214400; }
            else                   { src = sd; dst = sdo; off = i - 27262976; }
            float4 v = *(const float4*)(src + off);
            short4 s = { f2bf(v.x), f2bf(v.y), f2bf(v.z), f2bf(v.w) };
            *(short4*)(dst + off) = s;
        }
        return;
    }
    __shared__ float Xs[RTOK][H_DIM + 4];
    __shared__ float part[256];
    __shared__ float lg[RTOK][E_EXP];
    __shared__ int lcnt[E_EXP];
    const int b = blockIdx.x;
    const int t0 = b * RTOK;
    {
        int r = tid >> 5;
        int cb = (tid & 31) * 4;
        const float* xr = x + (size_t)(t0 + r) * H_DIM;
        short* xw = xbf + (size_t)(t0 + r) * H_DIM;
        #pragma unroll
        for (int j = 0; j < 8; ++j) {
            int c = cb + j * 128;
            float4 v = *(const float4*)(xr + c);
            *(float4*)&Xs[r][c] = v;
            short4 s = { f2bf(v.x), f2bf(v.y), f2bf(v.z), f2bf(v.w) };
            *(short4*)(xw + c) = s;
        }
    }
    __syncthreads();
    {
        int half = tid >> 7;
        int e    = (tid >> 3) & 15;
        int tok  = tid & 7;
        const float* wr  = rw + (size_t)e * H_DIM + half * 512;
        const float* xsr = &Xs[tok][half * 512];
        float acc = 0.f;
        #pragma unroll 4
        for (int k = 0; k < 512; k += 4) {
            float4 w = *(const float4*)(wr + k);
            float4 xv = *(const float4*)(xsr + k);
            acc += w.x * xv.x + w.y * xv.y + w.z * xv.z + w.w * xv.w;
        }
        part[tid] = acc;
    }
    __syncthreads();
    if (tid < 128) {
        float logit = part[tid] + part[tid + 128];
        lg[tid & 7][(tid >> 3) & 15] = logit;
    }
    if (tid < E_EXP) lcnt[tid] = 0;
    __syncthreads();
    if (tid < RTOK) {
        const int t = t0 + tid;
        float scores[E_EXP], sc[E_EXP];
        for (int e = 0; e < E_EXP; ++e) {
            float s = 1.f / (1.f + expf(-lg[tid][e]));
            scores[e] = s;
            sc[e] = s + ebias[e];
        }
        float gs[G_GRP];
        for (int gi = 0; gi < G_GRP; ++gi) {
            float v[4] = { sc[gi*4], sc[gi*4+1], sc[gi*4+2], sc[gi*4+3] };
            float b1 = -1e30f; int i1 = -1;
            for (int j = 0; j < 4; ++j) if (v[j] > b1) { b1 = v[j]; i1 = j; }
            float b2 = -1e30f;
            for (int j = 0; j < 4; ++j) if (j != i1 && v[j] > b2) b2 = v[j];
            gs[gi] = b1 + b2;
        }
        int g1 = -1; float b1 = -1e30f;
        for (int gi = 0; gi < G_GRP; ++gi) if (gs[gi] > b1) { b1 = gs[gi]; g1 = gi; }
        int g2 = -1; float b2 = -1e30f;
        for (int gi = 0; gi < G_GRP; ++gi) if (gi != g1 && gs[gi] > b2) { b2 = gs[gi]; g2 = gi; }
        float masked[E_EXP];
        for (int e = 0; e < E_EXP; ++e) {
            int grp = e >> 2;
            masked[e] = (grp == g1 || grp == g2) ? sc[e] : 0.f;
        }
        int tidx[K_TOP]; float tw[K_TOP];
        for (int k = 0; k < K_TOP; ++k) {
            int bi = -1; float bv = -1e30f;
            for (int e = 0; e < E_EXP; ++e) if (masked[e] > bv) { bv = masked[e]; bi = e; }
            tidx[k] = bi;
            tw[k] = scores[bi];
            masked[bi] = -1e30f;
        }
        float sum = tw[0] + tw[1] + tw[2] + tw[3];
        float inv = SCALE_F / (sum + 1e-20f);
        for (int k = 0; k < K_TOP; ++k) {
            int e = tidx[k];
            int p = atomicAdd(&lcnt[e], 1);          // LDS atomic, block-local
            blk_tok[(b * E_EXP + e) * 8 + p] = t;
            blk_wgt[(b * E_EXP + e) * 8 + p] = tw[k] * inv;
        }
    }
    __syncthreads();
    if (tid < E_EXP) blk_cnt[b * E_EXP + tid] = lcnt[tid];
}

// ================================================================ Dispatch 2: gateup
// bx <  512        : shared-expert MLP tile (always active)
// 512 <= bx < 4608 : routed tile (per-tile scan reconstructs expert token list)
// 4608 <= bx < 5120: zero out[] (8 MB) so the down kernel can be all-atomic
// bx >= 5120       : 16 densify blocks -> counts/lists/lweights for the down kernel
__global__ __launch_bounds__(256)
void moe_gateup(const short* __restrict__ Xbf,
                const int* __restrict__ blk_cnt, const int* __restrict__ blk_tok,
                const float* __restrict__ blk_wgt,
                const short* __restrict__ gw, const short* __restrict__ uw,
                const short* __restrict__ sgw, const short* __restrict__ suw,
                short* __restrict__ h_r, short* __restrict__ h_sh,
                float* __restrict__ out,
                int* __restrict__ counts, int* __restrict__ lists,
                float* __restrict__ lweights) {
    const int bx = blockIdx.x, tid = threadIdx.x;
    __shared__ __align__(16) short Xs[64*64], Gs[64*64], Us[64*64];   // 24 KB
    __shared__ int toks[64];
    __shared__ int sbuf[256];
    if (bx >= 5120) {
        // ---- densify: one block per expert; scan per-router-block counts, emit dense lists
        const int e = bx - 5120;
        int c = blk_cnt[tid * E_EXP + e];
        sbuf[tid] = c;
        __syncthreads();
        for (int off = 1; off < 256; off <<= 1) {
            int v = (tid >= off) ? sbuf[tid - off] : 0;
            __syncthreads();
            sbuf[tid] += v;
            __syncthreads();
        }
        int excl = sbuf[tid] - c;
        for (int j = 0; j < c; ++j) {
            lists[e * T_TOK + excl + j]    = blk_tok[(tid * E_EXP + e) * 8 + j];
            lweights[e * T_TOK + excl + j] = blk_wgt[(tid * E_EXP + e) * 8 + j];
        }
        if (tid == 255) counts[e] = sbuf[255];
        return;
    }
    if (bx >= 4608) {
        int z = bx - 4608;
        float4 zz = {0.f, 0.f, 0.f, 0.f};
        float4* o4 = (float4*)out + (size_t)z * 1024;
        #pragma unroll
        for (int i = 0; i < 4; ++i) o4[i * 256 + tid] = zz;
        return;
    }
    const short *gbase, *ubase; short* hout; int hpitch;
    if (bx >= 512) {
        int b2 = bx - 512;
        int e = b2 >> 8, mt = (b2 >> 3) & 31, nt = b2 & 7;
        int c = blk_cnt[tid * E_EXP + e];
        sbuf[tid] = c;
        if (tid < 64) toks[tid] = 0;
        __syncthreads();
        for (int off = 1; off < 256; off <<= 1) {
            int v = (tid >= off) ? sbuf[tid - off] : 0;
            __syncthreads();
            sbuf[tid] += v;
            __syncthreads();
        }
        int cnt = sbuf[255];
        if (mt * 64 >= cnt) return;
        int excl = sbuf[tid] - c;
        int lo = mt * 64;
        for (int j = 0; j < c; ++j) {
            int r = excl + j - lo;
            if (r >= 0 && r < 64) toks[r] = blk_tok[(tid * E_EXP + e) * 8 + j];
        }
        gbase = gw + (size_t)e * I_SZ * H_DIM + (size_t)(nt * 64) * H_DIM;
        ubase = uw + (size_t)e * I_SZ * H_DIM + (size_t)(nt * 64) * H_DIM;
        hout  = h_r + ((size_t)e * T_TOK + mt * 64) * I_SZ + nt * 64;
        hpitch = I_SZ;
    } else {
        int mt = bx >> 4, nt = bx & 15;
        if (tid < 64) toks[tid] = mt * 64 + tid;
        gbase = sgw + (size_t)(nt * 64) * H_DIM;
        ubase = suw + (size_t)(nt * 64) * H_DIM;
        hout  = h_sh + (size_t)(mt * 64) * 1024 + nt * 64;
        hpitch = 1024;
    }
    __syncthreads();

    const int lane = tid & 63, wv = tid >> 6;
    const int mw = wv & 1, nw = wv >> 1;
    const int lr = lane & 15, lq = lane >> 4;
    const int l3 = lane >> 3, l7 = lane & 7;
    const int seg = (l7 ^ l3) * 8;

    const int rowA = wv * 16 + l3, rowB = rowA + 8;
    const short* xA = Xbf   + (size_t)toks[rowA] * H_DIM + seg;
    const short* xB = Xbf   + (size_t)toks[rowB] * H_DIM + seg;
    const short* gA = gbase + (size_t)rowA * H_DIM + seg;
    const short* gB = gbase + (size_t)rowB * H_DIM + seg;
    const short* uA = ubase + (size_t)rowA * H_DIM + seg;
    const short* uB = ubase + (size_t)rowB * H_DIM + seg;
    short* ldsXA = &Xs[(wv*16    ) * 64]; short* ldsXB = &Xs[(wv*16 + 8) * 64];
    short* ldsGA = &Gs[(wv*16    ) * 64]; short* ldsGB = &Gs[(wv*16 + 8) * 64];
    short* ldsUA = &Us[(wv*16    ) * 64]; short* ldsUB = &Us[(wv*16 + 8) * 64];

    f32x4 accG[2][2], accU[2][2];
    #pragma unroll
    for (int a = 0; a < 2; ++a)
        #pragma unroll
        for (int b = 0; b < 2; ++b) {
            accG[a][b] = (f32x4){0.f,0.f,0.f,0.f};
            accU[a][b] = (f32x4){0.f,0.f,0.f,0.f};
        }

    #pragma unroll
    for (int c = 0; c < 16; ++c) {
        const int kc = c * 64;
        gld16(xA + kc, ldsXA); gld16(xB + kc, ldsXB);
        gld16(gA + kc, ldsGA); gld16(gB + kc, ldsGB);
        gld16(uA + kc, ldsUA); gld16(uB + kc, ldsUB);
        __syncthreads();
        #pragma unroll
        for (int kk = 0; kk < 64; kk += 32) {
            const int kf = kk + lq * 8;
            bfrag a0 = *(const bfrag*)&Xs[lds_idx(mw*32 + lr,      kf)];
            bfrag a1 = *(const bfrag*)&Xs[lds_idx(mw*32 + 16 + lr, kf)];
            bfrag g0 = *(const bfrag*)&Gs[lds_idx(nw*32 + lr,      kf)];
            bfrag g1 = *(const bfrag*)&Gs[lds_idx(nw*32 + 16 + lr, kf)];
            bfrag u0 = *(const bfrag*)&Us[lds_idx(nw*32 + lr,      kf)];
            bfrag u1 = *(const bfrag*)&Us[lds_idx(nw*32 + 16 + lr, kf)];
            accG[0][0] = MFMA16(a0, g0, accG[0][0]);
            accG[0][1] = MFMA16(a0, g1, accG[0][1]);
            accG[1][0] = MFMA16(a1, g0, accG[1][0]);
            accG[1][1] = MFMA16(a1, g1, accG[1][1]);
            accU[0][0] = MFMA16(a0, u0, accU[0][0]);
            accU[0][1] = MFMA16(a0, u1, accU[0][1]);
            accU[1][0] = MFMA16(a1, u0, accU[1][0]);
            accU[1][1] = MFMA16(a1, u1, accU[1][1]);
        }
        __syncthreads();
    }

    #pragma unroll
    for (int fm = 0; fm < 2; ++fm)
        #pragma unroll
        for (int fn = 0; fn < 2; ++fn)
            #pragma unroll
            for (int r = 0; r < 4; ++r) {
                int trow = mw*32 + fm*16 + lq*4 + r;
                int col  = nw*32 + fn*16 + lr;
                float g = accG[fm][fn][r], u = accU[fm][fn][r];
                hout[(size_t)trow * hpitch + col] = f2bf(g * u / (1.f + __expf(-g)));
            }
}

// ================================================================ Dispatch 3: down (merged)
// Round-0-proven shape (47.4 us): 64x64 tiles, dense lists (no scans), all-atomic
// onto out pre-zeroed by gateup's tail blocks. bx<8192 routed (K=512, weighted);
// else shared (K=1024, w=1).
__global__ __launch_bounds__(256)
void moe_down(const short* __restrict__ h_r, const short* __restrict__ h_sh,
              const int* __restrict__ counts, const int* __restrict__ lists,
              const float* __restrict__ lw, const short* __restrict__ dw,
              const short* __restrict__ shdw, float* __restrict__ out) {
    __shared__ __align__(16) short Hs[64*64], Ws[64*64];   // 16 KB
    __shared__ int toks[64];
    __shared__ float tws[64];
    const int bx = blockIdx.x, tid = threadIdx.x;
    const short *abase, *bbase; int apitch, K, n0;
    if (bx < 8192) {
        int e = bx >> 9, mt = (bx >> 4) & 31, nt = bx & 15;
        int cnt = counts[e];
        if (mt * 64 >= cnt) return;
        if (tid < 64) {
            int j = mt * 64 + tid;
            toks[tid] = (j < cnt) ? lists[e * T_TOK + j] : 0;
            tws[tid]  = (j < cnt) ? lw[e * T_TOK + j] : 0.f;
        }
        abase = h_r + ((size_t)e * T_TOK + mt * 64) * I_SZ;
        bbase = dw + (size_t)e * H_DIM * I_SZ + (size_t)(nt * 64) * I_SZ;
        apitch = I_SZ; K = I_SZ; n0 = nt * 64;
    } else {
        int b2 = bx - 8192, mt = b2 >> 4, nt = b2 & 15;
        if (tid < 64) { toks[tid] = mt * 64 + tid; tws[tid] = 1.f; }
        abase = h_sh + (size_t)(mt * 64) * 1024;
        bbase = shdw + (size_t)(nt * 64) * 1024;
        apitch = 1024; K = 1024; n0 = nt * 64;
    }
    __syncthreads();

    const int lane = tid & 63, wv = tid >> 6;
    const int mw = wv & 1, nw = wv >> 1;
    const int lr = lane & 15, lq = lane >> 4;
    const int l3 = lane >> 3, l7 = lane & 7;
    const int seg = (l7 ^ l3) * 8;

    const int rowA = wv * 16 + l3, rowB = rowA + 8;
    const short* aA = abase + (size_t)rowA * apitch + seg;
    const short* aB = abase + (size_t)rowB * apitch + seg;
    const short* bA = bbase + (size_t)rowA * apitch + seg;   // bpitch == apitch (== K)
    const short* bB = bbase + (size_t)rowB * apitch + seg;
    short* ldsHA = &Hs[(wv*16    ) * 64]; short* ldsHB = &Hs[(wv*16 + 8) * 64];
    short* ldsWA = &Ws[(wv*16    ) * 64]; short* ldsWB = &Ws[(wv*16 + 8) * 64];

    f32x4 acc[2][2];
    #pragma unroll
    for (int a = 0; a < 2; ++a)
        #pragma unroll
        for (int b = 0; b < 2; ++b) acc[a][b] = (f32x4){0.f,0.f,0.f,0.f};

    auto chunk = [&](int kc) {
        gld16(aA + kc, ldsHA); gld16(aB + kc, ldsHB);
        gld16(bA + kc, ldsWA); gld16(bB + kc, ldsWB);
        __syncthreads();
        #pragma unroll
        for (int kk = 0; kk < 64; kk += 32) {
            const int kf = kk + lq * 8;
            bfrag a0 = *(const bfrag*)&Hs[lds_idx(mw*32 + lr,      kf)];
            bfrag a1 = *(const bfrag*)&Hs[lds_idx(mw*32 + 16 + lr, kf)];
            bfrag b0 = *(const bfrag*)&Ws[lds_idx(nw*32 + lr,      kf)];
            bfrag b1 = *(const bfrag*)&Ws[lds_idx(nw*32 + 16 + lr, kf)];
            acc[0][0] = MFMA16(a0, b0, acc[0][0]);
            acc[0][1] = MFMA16(a0, b1, acc[0][1]);
            acc[1][0] = MFMA16(a1, b0, acc[1][0]);
            acc[1][1] = MFMA16(a1, b1, acc[1][1]);
        }
        __syncthreads();
    };
    #pragma unroll
    for (int c = 0; c < 8; ++c) chunk(c * 64);
    if (K == 1024) {
        #pragma unroll
        for (int c = 8; c < 16; ++c) chunk(c * 64);
    }

    #pragma unroll
    for (int fm = 0; fm < 2; ++fm)
        #pragma unroll
        for (int fn = 0; fn < 2; ++fn)
            #pragma unroll
            for (int r = 0; r < 4; ++r) {
                int trow = mw*32 + fm*16 + lq*4 + r;
                int col  = n0 + nw*32 + fn*16 + lr;
                float w = tws[trow];
                if (w != 0.f)
                    atomicAdd(out + (size_t)toks[trow] * H_DIM + col, acc[fm][fn][r] * w);
            }
}

// ---------------------------------------------------------------- fp32 fallback (small ws)
__global__ void zero_kernel(float* __restrict__ out, int n4, int* __restrict__ counts) {
    int i = blockIdx.x * blockDim.x + threadIdx.x;
    if (i < n4) {
        float4 z = {0.f, 0.f, 0.f, 0.f};
        *(float4*)(out + (size_t)i * 4) = z;
    }
    if (blockIdx.x == 0 && threadIdx.x < E_EXP) counts[threadIdx.x] = 0;
}

__global__ __launch_bounds__(256)
void router_legacy(const float* __restrict__ x, const float* __restrict__ rw,
                   const float* __restrict__ ebias, int* __restrict__ counts,
                   int* __restrict__ lists, float* __restrict__ lweights) {
    __shared__ float Xs[RTOK][H_DIM + 4];
    __shared__ float part[256];
    __shared__ float lg[RTOK][E_EXP];
    const int tid = threadIdx.x;
    const int t0 = blockIdx.x * RTOK;
    {
        int r = tid >> 5;
        int cb = (tid & 31) * 4;
        const float* xr = x + (size_t)(t0 + r) * H_DIM;
        #pragma unroll
        for (int j = 0; j < 8; ++j) {
            int c = cb + j * 128;
            *(float4*)&Xs[r][c] = *(const float4*)(xr + c);
        }
    }
    __syncthreads();
    {
        int half = tid >> 7;
        int e    = (tid >> 3) & 15;
        int tok  = tid & 7;
        const float* wr  = rw + (size_t)e * H_DIM + half * 512;
        const float* xsr = &Xs[tok][half * 512];
        float acc = 0.f;
        #pragma unroll 4
        for (int k = 0; k < 512; k += 4) {
            float4 w = *(const float4*)(wr + k);
            float4 xv = *(const float4*)(xsr + k);
            acc += w.x * xv.x + w.y * xv.y + w.z * xv.z + w.w * xv.w;
        }
        part[tid] = acc;
    }
    __syncthreads();
    if (tid < 128) {
        float logit = part[tid] + part[tid + 128];
        lg[tid & 7][(tid >> 3) & 15] = logit;
    }
    __syncthreads();
    if (tid >= RTOK) return;
    const int t = t0 + tid;
    float scores[E_EXP], sc[E_EXP];
    for (int e = 0; e < E_EXP; ++e) {
        float s = 1.f / (1.f + expf(-lg[tid][e]));
        scores[e] = s;
        sc[e] = s + ebias[e];
    }
    float gs[G_GRP];
    for (int g = 0; g < G_GRP; ++g) {
        float v[4] = { sc[g*4], sc[g*4+1], sc[g*4+2], sc[g*4+3] };
        float b1 = -1e30f; int i1 = -1;
        for (int j = 0; j < 4; ++j) if (v[j] > b1) { b1 = v[j]; i1 = j; }
        float b2 = -1e30f;
        for (int j = 0; j < 4; ++j) if (j != i1 && v[j] > b2) b2 = v[j];
        gs[g] = b1 + b2;
    }
    int g1 = -1; float b1 = -1e30f;
    for (int g = 0; g < G_GRP; ++g) if (gs[g] > b1) { b1 = gs[g]; g1 = g; }
    int g2 = -1; float b2 = -1e30f;
    for (int g = 0; g < G_GRP; ++g) if (g != g1 && gs[g] > b2) { b2 = gs[g]; g2 = g; }
    float masked[E_EXP];
    for (int e = 0; e < E_EXP; ++e) {
        int grp = e >> 2;
        masked[e] = (grp == g1 || grp == g2) ? sc[e] : 0.f;
    }
    int tidx[K_TOP]; float tw[K_TOP];
    for (int k = 0; k < K_TOP; ++k) {
        int bi = -1; float bv = -1e30f;
        for (int e = 0; e < E_EXP; ++e) if (masked[e] > bv) { bv = masked[e]; bi = e; }
        tidx[k] = bi;
        tw[k] = scores[bi];
        masked[bi] = -1e30f;
    }
    float sum = tw[0] + tw[1] + tw[2] + tw[3];
    float inv = SCALE_F / (sum + 1e-20f);
    for (int k = 0; k < K_TOP; ++k) {
        int e = tidx[k];
        int pos = atomicAdd(&counts[e], 1);
        lists[e * T_TOK + pos] = t;
        lweights[e * T_TOK + pos] = tw[k] * inv;
    }
}

__device__ __forceinline__ bfrag load_wfrag_f(const float* p) {
    float4 a = *(const float4*)(p);
    float4 b = *(const float4*)(p + 4);
    bfrag r;
    r[0]=f2bf(a.x); r[1]=f2bf(a.y); r[2]=f2bf(a.z); r[3]=f2bf(a.w);
    r[4]=f2bf(b.x); r[5]=f2bf(b.y); r[6]=f2bf(b.z); r[7]=f2bf(b.w);
    return r;
}

#define TM 32
__global__ __launch_bounds__(256)
void moe_gemm_fb(const float* __restrict__ x,
                 const float* __restrict__ gate_w, const float* __restrict__ up_w,
                 const float* __restrict__ down_w, const float* __restrict__ sh_gate,
                 const float* __restrict__ sh_up, const float* __restrict__ sh_down,
                 const int* __restrict__ counts, const int* __restrict__ lists,
                 const float* __restrict__ lweights, float* __restrict__ out) {
    const int bx = blockIdx.x;
    const int e = bx >> 6;
    const int tile = bx & 63;
    int ntok; const float *gp, *upp, *dpp; int dpitch;
    if (e < E_EXP) {
        ntok = counts[e];
        gp  = gate_w + (size_t)e * I_SZ * H_DIM;
        upp = up_w   + (size_t)e * I_SZ * H_DIM;
        dpp = down_w + (size_t)e * H_DIM * I_SZ;
        dpitch = I_SZ;
    } else {
        int s = e - E_EXP;
        ntok = T_TOK;
        gp  = sh_gate + (size_t)s * I_SZ * H_DIM;
        upp = sh_up   + (size_t)s * I_SZ * H_DIM;
        dpp = sh_down + (size_t)s * I_SZ;
        dpitch = 2 * I_SZ;
    }
    const int start = tile * TM;
    if (start >= ntok) return;

    __shared__ __align__(16) short Xs2[TM][H_DIM + 8];
    __shared__ __align__(16) short Hs2[TM][I_SZ + 8];
    __shared__ int   toks[TM];
    __shared__ float tws[TM];

    const int tid = threadIdx.x;
    if (tid < TM) {
        int j = start + tid;
        int tok = 0; float w = 0.f;
        if (j < ntok) {
            if (e < E_EXP) { tok = lists[e * T_TOK + j]; w = lweights[e * T_TOK + j]; }
            else           { tok = j;                    w = 1.0f; }
        }
        toks[tid] = tok; tws[tid] = w;
    }
    __syncthreads();
    {
        int r = tid >> 3;
        int c0 = (tid & 7) * 128;
        const float* xr = x + (size_t)toks[r] * H_DIM + c0;
        #pragma unroll
        for (int c = 0; c < 128; c += 4) {
            float4 v = *(const float4*)(xr + c);
            short4 s = { f2bf(v.x), f2bf(v.y), f2bf(v.z), f2bf(v.w) };
            *(short4*)&Xs2[r][c0 + c] = s;
        }
    }
    __syncthreads();

    const int lane = tid & 63;
    const int wv   = tid >> 6;
    const int lr   = lane & 15;
    const int lq   = lane >> 4;
    const int ko   = lq * 8;

    for (int it = 0; it < I_SZ / 64; ++it) {
        const int i0 = wv * (I_SZ / 4) + it * 16;
        const float* grow = gp  + (size_t)(i0 + lr) * H_DIM;
        const float* urow = upp + (size_t)(i0 + lr) * H_DIM;
        f32x4 aG0 = {0.f,0.f,0.f,0.f}, aU0 = {0.f,0.f,0.f,0.f};
        f32x4 aG1 = {0.f,0.f,0.f,0.f}, aU1 = {0.f,0.f,0.f,0.f};
        for (int k0 = 0; k0 < H_DIM; k0 += 32) {
            bfrag bg = load_wfrag_f(grow + k0 + ko);
            bfrag bu = load_wfrag_f(urow + k0 + ko);
            bfrag a0 = *(const bfrag*)&Xs2[lr][k0 + ko];
            bfrag a1 = *(const bfrag*)&Xs2[lr + 16][k0 + ko];
            aG0 = MFMA16(a0, bg, aG0);
            aG1 = MFMA16(a1, bg, aG1);
            aU0 = MFMA16(a0, bu, aU0);
            aU1 = MFMA16(a1, bu, aU1);
        }
        #pragma unroll
        for (int r = 0; r < 4; ++r) {
            const int trow = lq * 4 + r;
            float g0 = aG0[r], u0 = aU0[r];
            Hs2[trow][i0 + lr] = f2bf(g0 * u0 / (1.f + __expf(-g0)));
            float g1 = aG1[r], u1 = aU1[r];
            Hs2[trow + 16][i0 + lr] = f2bf(g1 * u1 / (1.f + __expf(-g1)));
        }
    }
    __syncthreads();

    for (int ct = 0; ct < H_DIM / 64; ++ct) {
        const int c0 = wv * (H_DIM / 4) + ct * 16;
        const float* drow = dpp + (size_t)(c0 + lr) * dpitch;
        f32x4 a0 = {0.f,0.f,0.f,0.f}, a1 = {0.f,0.f,0.f,0.f};
        for (int k0 = 0; k0 < I_SZ; k0 += 32) {
            bfrag bd = load_wfrag_f(drow + k0 + ko);
            bfrag h0 = *(const bfrag*)&Hs2[lr][k0 + ko];
            bfrag h1 = *(const bfrag*)&Hs2[lr + 16][k0 + ko];
            a0 = MFMA16(h0, bd, a0);
            a1 = MFMA16(h1, bd, a1);
        }
        #pragma unroll
        for (int r = 0; r < 4; ++r) {
            const int trow = lq * 4 + r;
            float w0 = tws[trow], w1 = tws[trow + 16];
            if (w0 != 0.f) atomicAdd(out + (size_t)toks[trow] * H_DIM + c0 + lr, a0[r] * w0);
            if (w1 != 0.f) atomicAdd(out + (size_t)toks[trow + 16] * H_DIM + c0 + lr, a1[r] * w1);
        }
    }
}

// ---------------------------------------------------------------- launch
extern "C" void kernel_launch(void* const* d_in, const int* in_sizes, int n_in,
                              void* d_out, int out_size, void* d_ws, size_t ws_size,
                              hipStream_t stream) {
    const float* x     = (const float*)d_in[0];
    const float* rw    = (const float*)d_in[1];
    const float* ebias = (const float*)d_in[2];
    const float* gate_w = (const float*)d_in[3];
    const float* up_w   = (const float*)d_in[4];
    const float* down_w = (const float*)d_in[5];
    const float* shg    = (const float*)d_in[6];
    const float* shu    = (const float*)d_in[7];
    const float* shd    = (const float*)d_in[8];
    float* out = (float*)d_out;

    char* ws = (char*)d_ws;
    int*   blk_cnt = (int*)ws;                        // 16 KB
    int*   blk_tok = (int*)(ws + 16384);              // 128 KB
    float* blk_wgt = (float*)(ws + 16384 + 131072);   // 128 KB
    int*   counts  = (int*)(ws + 278528);             // 1 KB
    int*   lists   = (int*)(ws + 279552);             // 128 KB
    float* lw      = (float*)(ws + 279552 + 131072);  // 128 KB
    size_t off = 279552 + 131072 + 131072;            // 541696

    const size_t n_gu = (size_t)E_EXP * I_SZ * H_DIM;   // 8388608
    const size_t n_sh = (size_t)H_DIM * 1024;           // 1048576
    const size_t n_x  = (size_t)T_TOK * H_DIM;          // 2097152

    short* g_bf  = (short*)(ws + off); off += n_gu * 2;
    short* u_bf  = (short*)(ws + off); off += n_gu * 2;
    short* d_bf  = (short*)(ws + off); off += n_gu * 2;
    short* sg_bf = (short*)(ws + off); off += n_sh * 2;
    short* su_bf = (short*)(ws + off); off += n_sh * 2;
    short* sd_bf = (short*)(ws + off); off += n_sh * 2;
    short* x_bf  = (short*)(ws + off); off += n_x * 2;
    short* h_r   = (short*)(ws + off); off += (size_t)E_EXP * T_TOK * I_SZ * 2;  // 32 MB
    short* h_sh  = (short*)(ws + off); off += (size_t)T_TOK * 1024 * 2;          // 4 MB
    const size_t need = off;

    if (ws_size >= need) {
        prep<<<256 + 3456, 256, 0, stream>>>(x, rw, ebias,
                                             gate_w, up_w, down_w, shg, shu, shd,
                                             g_bf, u_bf, d_bf, sg_bf, su_bf, sd_bf,
                                             x_bf, blk_cnt, blk_tok, blk_wgt);
        moe_gateup<<<512 + 4096 + 512 + 16, 256, 0, stream>>>(x_bf, blk_cnt, blk_tok, blk_wgt,
                                                              g_bf, u_bf, sg_bf, su_bf,
                                                              h_r, h_sh, out,
                                                              counts, lists, lw);
        moe_down<<<8192 + 512, 256, 0, stream>>>(h_r, h_sh, counts, lists, lw,
                                                 d_bf, sd_bf, out);
    } else {
        zero_kernel<<<(out_size / 4 + 255) / 256, 256, 0, stream>>>(out, out_size / 4, counts);
        router_legacy<<<T_TOK / RTOK, 256, 0, stream>>>(x, rw, ebias, counts, lists, lw);
        moe_gemm_fb<<<(E_EXP + 2) * 64, 256, 0, stream>>>(x, gate_w, up_w, down_w,
                                                          shg, shu, shd, counts, lists, lw, out);
    }
}

// Round 9
// 243.709 us; speedup vs baseline: 2.6718x; 1.0139x over previous
//
#include <hip/hip_runtime.h>
#include <hip/hip_bf16.h>
#include <math.h>

// Problem constants (DeepseekV3MoE reference)
#define T_TOK 2048
#define H_DIM 1024
#define E_EXP 16
#define K_TOP 4
#define G_GRP 4
#define I_SZ 512
#define SCALE_F 2.5f

typedef __attribute__((ext_vector_type(8))) short bfrag;    // 8 bf16 (4 VGPR)
typedef __attribute__((ext_vector_type(4))) float f32x4;    // MFMA acc

#define MFMA16(a, b, c) __builtin_amdgcn_mfma_f32_16x16x32_bf16(a, b, c, 0, 0, 0)

__device__ __forceinline__ short f2bf(float f) {
    union { float f; unsigned u; } v; v.f = f;
    unsigned u = v.u;
    u += 0x7fffu + ((u >> 16) & 1u);   // RNE
    return (short)(u >> 16);
}

// XOR-swizzled LDS index for 64-short rows (verified conflict-free).
__device__ __forceinline__ int lds_idx(int row, int k) {
    return row * 64 + ((((k >> 3) ^ (row & 7))) << 3) + (k & 7);
}

typedef __attribute__((address_space(1))) unsigned int as1_u32;
typedef __attribute__((address_space(3))) unsigned int as3_u32;
__device__ __forceinline__ void gld16(const short* g, short* l) {
    __builtin_amdgcn_global_load_lds((const as1_u32*)g, (as3_u32*)l, 16, 0, 0);
}

#define RTOK 8
#define CV_CHUNKS 7077888L   // 28311552 elems / 4

// ================================================================ Dispatch 1: prep
// blocks 0..255: router (atomic-free: per-block dense expert lists, no init needed)
// blocks 256+ : fp32->bf16 conversion of all weights (grid-stride) + zero out[]
__global__ __launch_bounds__(256)
void prep(const float* __restrict__ x, const float* __restrict__ rw,
          const float* __restrict__ ebias,
          const float* __restrict__ g, const float* __restrict__ u, const float* __restrict__ d,
          const float* __restrict__ sg, const float* __restrict__ su, const float* __restrict__ sd,
          short* __restrict__ go, short* __restrict__ uo, short* __restrict__ dd,
          short* __restrict__ sgo, short* __restrict__ suo, short* __restrict__ sdo,
          short* __restrict__ xbf,
          int* __restrict__ blk_cnt, int* __restrict__ blk_tok, float* __restrict__ blk_wgt,
          float* __restrict__ out) {
    const int tid = threadIdx.x;
    if (blockIdx.x >= 256) {
        const long NB = (long)gridDim.x - 256;
        const long step = NB * 256;
        for (long c = ((long)blockIdx.x - 256) * 256 + tid; c < CV_CHUNKS; c += step) {
            long i = c * 4;
            const float* src; short* dst; long off;
            if      (i < 8388608)  { src = g;  dst = go;  off = i; }
            else if (i < 16777216) { src = u;  dst = uo;  off = i - 8388608; }
            else if (i < 25165824) { src = d;  dst = dd;  off = i - 16777216; }
            else if (i < 26214400) { src = sg; dst = sgo; off = i - 25165824; }
            else if (i < 27262976) { src = su; dst = suo; off = i - 26214400; }
            else                   { src = sd; dst = sdo; off = i - 27262976; }
            float4 v = *(const float4*)(src + off);
            short4 s = { f2bf(v.x), f2bf(v.y), f2bf(v.z), f2bf(v.w) };
            *(short4*)(dst + off) = s;
        }
        // zero out[] (8 MB) so the down kernel can be all-atomic
        float4 zz = {0.f, 0.f, 0.f, 0.f};
        for (long i = ((long)blockIdx.x - 256) * 256 + tid; i < 524288; i += step)
            *((float4*)out + i) = zz;
        return;
    }
    __shared__ float Xs[RTOK][H_DIM + 4];
    __shared__ float part[256];
    __shared__ float lg[RTOK][E_EXP];
    __shared__ int lcnt[E_EXP];
    const int b = blockIdx.x;
    const int t0 = b * RTOK;
    {
        int r = tid >> 5;
        int cb = (tid & 31) * 4;
        const float* xr = x + (size_t)(t0 + r) * H_DIM;
        short* xw = xbf + (size_t)(t0 + r) * H_DIM;
        #pragma unroll
        for (int j = 0; j < 8; ++j) {
            int c = cb + j * 128;
            float4 v = *(const float4*)(xr + c);
            *(float4*)&Xs[r][c] = v;
            short4 s = { f2bf(v.x), f2bf(v.y), f2bf(v.z), f2bf(v.w) };
            *(short4*)(xw + c) = s;
        }
    }
    __syncthreads();
    {
        int half = tid >> 7;
        int e    = (tid >> 3) & 15;
        int tok  = tid & 7;
        const float* wr  = rw + (size_t)e * H_DIM + half * 512;
        const float* xsr = &Xs[tok][half * 512];
        float acc = 0.f;
        #pragma unroll 4
        for (int k = 0; k < 512; k += 4) {
            float4 w = *(const float4*)(wr + k);
            float4 xv = *(const float4*)(xsr + k);
            acc += w.x * xv.x + w.y * xv.y + w.z * xv.z + w.w * xv.w;
        }
        part[tid] = acc;
    }
    __syncthreads();
    if (tid < 128) {
        float logit = part[tid] + part[tid + 128];
        lg[tid & 7][(tid >> 3) & 15] = logit;
    }
    if (tid < E_EXP) lcnt[tid] = 0;
    __syncthreads();
    if (tid < RTOK) {
        const int t = t0 + tid;
        float scores[E_EXP], sc[E_EXP];
        for (int e = 0; e < E_EXP; ++e) {
            float s = 1.f / (1.f + expf(-lg[tid][e]));
            scores[e] = s;
            sc[e] = s + ebias[e];
        }
        float gs[G_GRP];
        for (int gi = 0; gi < G_GRP; ++gi) {
            float v[4] = { sc[gi*4], sc[gi*4+1], sc[gi*4+2], sc[gi*4+3] };
            float b1 = -1e30f; int i1 = -1;
            for (int j = 0; j < 4; ++j) if (v[j] > b1) { b1 = v[j]; i1 = j; }
            float b2 = -1e30f;
            for (int j = 0; j < 4; ++j) if (j != i1 && v[j] > b2) b2 = v[j];
            gs[gi] = b1 + b2;
        }
        int g1 = -1; float b1 = -1e30f;
        for (int gi = 0; gi < G_GRP; ++gi) if (gs[gi] > b1) { b1 = gs[gi]; g1 = gi; }
        int g2 = -1; float b2 = -1e30f;
        for (int gi = 0; gi < G_GRP; ++gi) if (gi != g1 && gs[gi] > b2) { b2 = gs[gi]; g2 = gi; }
        float masked[E_EXP];
        for (int e = 0; e < E_EXP; ++e) {
            int grp = e >> 2;
            masked[e] = (grp == g1 || grp == g2) ? sc[e] : 0.f;
        }
        int tidx[K_TOP]; float tw[K_TOP];
        for (int k = 0; k < K_TOP; ++k) {
            int bi = -1; float bv = -1e30f;
            for (int e = 0; e < E_EXP; ++e) if (masked[e] > bv) { bv = masked[e]; bi = e; }
            tidx[k] = bi;
            tw[k] = scores[bi];
            masked[bi] = -1e30f;
        }
        float sum = tw[0] + tw[1] + tw[2] + tw[3];
        float inv = SCALE_F / (sum + 1e-20f);
        for (int k = 0; k < K_TOP; ++k) {
            int e = tidx[k];
            int p = atomicAdd(&lcnt[e], 1);          // LDS atomic, block-local
            blk_tok[(b * E_EXP + e) * 8 + p] = t;
            blk_wgt[(b * E_EXP + e) * 8 + p] = tw[k] * inv;
        }
    }
    __syncthreads();
    if (tid < E_EXP) blk_cnt[b * E_EXP + tid] = lcnt[tid];
}

// ================================================================ Dispatch 2: gateup
// bx <  512        : shared-expert MLP tile (always active, natural order)
// 512 <= bx < 4608 : routed tile, EXPERT->XCD AFFINE: physical r = widx*8 + (e&7)
//                    so both experts {e, e+8} live on XCD e%8 and weight/X
//                    re-reads (each ~8x) hit that XCD's L2 instead of L3.
//                    Balanced: every XCD gets exactly 2 experts x identical
//                    tile structure (round-1 failure was a CLUSTERED mapping).
// bx >= 4608       : 16 densify blocks -> counts/lists/lweights for down
__global__ __launch_bounds__(256)
void moe_gateup(const short* __restrict__ Xbf,
                const int* __restrict__ blk_cnt, const int* __restrict__ blk_tok,
                const float* __restrict__ blk_wgt,
                const short* __restrict__ gw, const short* __restrict__ uw,
                const short* __restrict__ sgw, const short* __restrict__ suw,
                short* __restrict__ h_r, short* __restrict__ h_sh,
                int* __restrict__ counts, int* __restrict__ lists,
                float* __restrict__ lweights) {
    const int bx = blockIdx.x, tid = threadIdx.x;
    __shared__ __align__(16) short Xs[64*64], Gs[64*64], Us[64*64];   // 24 KB
    __shared__ int toks[64];
    __shared__ int sbuf[256];
    if (bx >= 4608) {
        // ---- densify: one block per expert; scan per-router-block counts, emit dense lists
        const int e = bx - 4608;
        int c = blk_cnt[tid * E_EXP + e];
        sbuf[tid] = c;
        __syncthreads();
        for (int off = 1; off < 256; off <<= 1) {
            int v = (tid >= off) ? sbuf[tid - off] : 0;
            __syncthreads();
            sbuf[tid] += v;
            __syncthreads();
        }
        int excl = sbuf[tid] - c;
        for (int j = 0; j < c; ++j) {
            lists[e * T_TOK + excl + j]    = blk_tok[(tid * E_EXP + e) * 8 + j];
            lweights[e * T_TOK + excl + j] = blk_wgt[(tid * E_EXP + e) * 8 + j];
        }
        if (tid == 255) counts[e] = sbuf[255];
        return;
    }
    const short *gbase, *ubase; short* hout; int hpitch;
    if (bx >= 512) {
        int r = bx - 512;                 // [0, 4096)
        int xcd  = r & 7;                 // = e & 7
        int widx = r >> 3;                // [0, 512)
        int e  = ((widx >> 8) << 3) | xcd;
        int rem = widx & 255;
        int mt = rem >> 3, nt = rem & 7;
        int c = blk_cnt[tid * E_EXP + e];
        sbuf[tid] = c;
        if (tid < 64) toks[tid] = 0;
        __syncthreads();
        for (int off = 1; off < 256; off <<= 1) {
            int v = (tid >= off) ? sbuf[tid - off] : 0;
            __syncthreads();
            sbuf[tid] += v;
            __syncthreads();
        }
        int cnt = sbuf[255];
        if (mt * 64 >= cnt) return;
        int excl = sbuf[tid] - c;
        int lo = mt * 64;
        for (int j = 0; j < c; ++j) {
            int rr = excl + j - lo;
            if (rr >= 0 && rr < 64) toks[rr] = blk_tok[(tid * E_EXP + e) * 8 + j];
        }
        gbase = gw + (size_t)e * I_SZ * H_DIM + (size_t)(nt * 64) * H_DIM;
        ubase = uw + (size_t)e * I_SZ * H_DIM + (size_t)(nt * 64) * H_DIM;
        hout  = h_r + ((size_t)e * T_TOK + mt * 64) * I_SZ + nt * 64;
        hpitch = I_SZ;
    } else {
        int mt = bx >> 4, nt = bx & 15;
        if (tid < 64) toks[tid] = mt * 64 + tid;
        gbase = sgw + (size_t)(nt * 64) * H_DIM;
        ubase = suw + (size_t)(nt * 64) * H_DIM;
        hout  = h_sh + (size_t)(mt * 64) * 1024 + nt * 64;
        hpitch = 1024;
    }
    __syncthreads();

    const int lane = tid & 63, wv = tid >> 6;
    const int mw = wv & 1, nw = wv >> 1;
    const int lr = lane & 15, lq = lane >> 4;
    const int l3 = lane >> 3, l7 = lane & 7;
    const int seg = (l7 ^ l3) * 8;

    const int rowA = wv * 16 + l3, rowB = rowA + 8;
    const short* xA = Xbf   + (size_t)toks[rowA] * H_DIM + seg;
    const short* xB = Xbf   + (size_t)toks[rowB] * H_DIM + seg;
    const short* gA = gbase + (size_t)rowA * H_DIM + seg;
    const short* gB = gbase + (size_t)rowB * H_DIM + seg;
    const short* uA = ubase + (size_t)rowA * H_DIM + seg;
    const short* uB = ubase + (size_t)rowB * H_DIM + seg;
    short* ldsXA = &Xs[(wv*16    ) * 64]; short* ldsXB = &Xs[(wv*16 + 8) * 64];
    short* ldsGA = &Gs[(wv*16    ) * 64]; short* ldsGB = &Gs[(wv*16 + 8) * 64];
    short* ldsUA = &Us[(wv*16    ) * 64]; short* ldsUB = &Us[(wv*16 + 8) * 64];

    f32x4 accG[2][2], accU[2][2];
    #pragma unroll
    for (int a = 0; a < 2; ++a)
        #pragma unroll
        for (int b = 0; b < 2; ++b) {
            accG[a][b] = (f32x4){0.f,0.f,0.f,0.f};
            accU[a][b] = (f32x4){0.f,0.f,0.f,0.f};
        }

    #pragma unroll
    for (int c = 0; c < 16; ++c) {
        const int kc = c * 64;
        gld16(xA + kc, ldsXA); gld16(xB + kc, ldsXB);
        gld16(gA + kc, ldsGA); gld16(gB + kc, ldsGB);
        gld16(uA + kc, ldsUA); gld16(uB + kc, ldsUB);
        __syncthreads();
        #pragma unroll
        for (int kk = 0; kk < 64; kk += 32) {
            const int kf = kk + lq * 8;
            bfrag a0 = *(const bfrag*)&Xs[lds_idx(mw*32 + lr,      kf)];
            bfrag a1 = *(const bfrag*)&Xs[lds_idx(mw*32 + 16 + lr, kf)];
            bfrag g0 = *(const bfrag*)&Gs[lds_idx(nw*32 + lr,      kf)];
            bfrag g1 = *(const bfrag*)&Gs[lds_idx(nw*32 + 16 + lr, kf)];
            bfrag u0 = *(const bfrag*)&Us[lds_idx(nw*32 + lr,      kf)];
            bfrag u1 = *(const bfrag*)&Us[lds_idx(nw*32 + 16 + lr, kf)];
            accG[0][0] = MFMA16(a0, g0, accG[0][0]);
            accG[0][1] = MFMA16(a0, g1, accG[0][1]);
            accG[1][0] = MFMA16(a1, g0, accG[1][0]);
            accG[1][1] = MFMA16(a1, g1, accG[1][1]);
            accU[0][0] = MFMA16(a0, u0, accU[0][0]);
            accU[0][1] = MFMA16(a0, u1, accU[0][1]);
            accU[1][0] = MFMA16(a1, u0, accU[1][0]);
            accU[1][1] = MFMA16(a1, u1, accU[1][1]);
        }
        __syncthreads();
    }

    #pragma unroll
    for (int fm = 0; fm < 2; ++fm)
        #pragma unroll
        for (int fn = 0; fn < 2; ++fn)
            #pragma unroll
            for (int r = 0; r < 4; ++r) {
                int trow = mw*32 + fm*16 + lq*4 + r;
                int col  = nw*32 + fn*16 + lr;
                float g = accG[fm][fn][r], u = accU[fm][fn][r];
                hout[(size_t)trow * hpitch + col] = f2bf(g * u / (1.f + __expf(-g)));
            }
}

// ================================================================ Dispatch 3: down (merged)
// 64x64 tiles, dense lists (no scans), all-atomic onto out pre-zeroed in prep.
// Routed tiles expert->XCD affine (dw 2MB + h_r ~1MB per XCD-pair fits 4MB L2).
__global__ __launch_bounds__(256)
void moe_down(const short* __restrict__ h_r, const short* __restrict__ h_sh,
              const int* __restrict__ counts, const int* __restrict__ lists,
              const float* __restrict__ lw, const short* __restrict__ dw,
              const short* __restrict__ shdw, float* __restrict__ out) {
    __shared__ __align__(16) short Hs[64*64], Ws[64*64];   // 16 KB
    __shared__ int toks[64];
    __shared__ float tws[64];
    const int bx = blockIdx.x, tid = threadIdx.x;
    const short *abase, *bbase; int apitch, K, n0;
    if (bx < 8192) {
        int xcd  = bx & 7;                 // = e & 7
        int widx = bx >> 3;                // [0, 1024)
        int e  = ((widx >> 9) << 3) | xcd;
        int rem = widx & 511;
        int mt = rem >> 4, nt = rem & 15;
        int cnt = counts[e];
        if (mt * 64 >= cnt) return;
        if (tid < 64) {
            int j = mt * 64 + tid;
            toks[tid] = (j < cnt) ? lists[e * T_TOK + j] : 0;
            tws[tid]  = (j < cnt) ? lw[e * T_TOK + j] : 0.f;
        }
        abase = h_r + ((size_t)e * T_TOK + mt * 64) * I_SZ;
        bbase = dw + (size_t)e * H_DIM * I_SZ + (size_t)(nt * 64) * I_SZ;
        apitch = I_SZ; K = I_SZ; n0 = nt * 64;
    } else {
        int b2 = bx - 8192, mt = b2 >> 4, nt = b2 & 15;
        if (tid < 64) { toks[tid] = mt * 64 + tid; tws[tid] = 1.f; }
        abase = h_sh + (size_t)(mt * 64) * 1024;
        bbase = shdw + (size_t)(nt * 64) * 1024;
        apitch = 1024; K = 1024; n0 = nt * 64;
    }
    __syncthreads();

    const int lane = tid & 63, wv = tid >> 6;
    const int mw = wv & 1, nw = wv >> 1;
    const int lr = lane & 15, lq = lane >> 4;
    const int l3 = lane >> 3, l7 = lane & 7;
    const int seg = (l7 ^ l3) * 8;

    const int rowA = wv * 16 + l3, rowB = rowA + 8;
    const short* aA = abase + (size_t)rowA * apitch + seg;
    const short* aB = abase + (size_t)rowB * apitch + seg;
    const short* bA = bbase + (size_t)rowA * apitch + seg;   // bpitch == apitch (== K)
    const short* bB = bbase + (size_t)rowB * apitch + seg;
    short* ldsHA = &Hs[(wv*16    ) * 64]; short* ldsHB = &Hs[(wv*16 + 8) * 64];
    short* ldsWA = &Ws[(wv*16    ) * 64]; short* ldsWB = &Ws[(wv*16 + 8) * 64];

    f32x4 acc[2][2];
    #pragma unroll
    for (int a = 0; a < 2; ++a)
        #pragma unroll
        for (int b = 0; b < 2; ++b) acc[a][b] = (f32x4){0.f,0.f,0.f,0.f};

    auto chunk = [&](int kc) {
        gld16(aA + kc, ldsHA); gld16(aB + kc, ldsHB);
        gld16(bA + kc, ldsWA); gld16(bB + kc, ldsWB);
        __syncthreads();
        #pragma unroll
        for (int kk = 0; kk < 64; kk += 32) {
            const int kf = kk + lq * 8;
            bfrag a0 = *(const bfrag*)&Hs[lds_idx(mw*32 + lr,      kf)];
            bfrag a1 = *(const bfrag*)&Hs[lds_idx(mw*32 + 16 + lr, kf)];
            bfrag b0 = *(const bfrag*)&Ws[lds_idx(nw*32 + lr,      kf)];
            bfrag b1 = *(const bfrag*)&Ws[lds_idx(nw*32 + 16 + lr, kf)];
            acc[0][0] = MFMA16(a0, b0, acc[0][0]);
            acc[0][1] = MFMA16(a0, b1, acc[0][1]);
            acc[1][0] = MFMA16(a1, b0, acc[1][0]);
            acc[1][1] = MFMA16(a1, b1, acc[1][1]);
        }
        __syncthreads();
    };
    #pragma unroll
    for (int c = 0; c < 8; ++c) chunk(c * 64);
    if (K == 1024) {
        #pragma unroll
        for (int c = 8; c < 16; ++c) chunk(c * 64);
    }

    #pragma unroll
    for (int fm = 0; fm < 2; ++fm)
        #pragma unroll
        for (int fn = 0; fn < 2; ++fn)
            #pragma unroll
            for (int r = 0; r < 4; ++r) {
                int trow = mw*32 + fm*16 + lq*4 + r;
                int col  = n0 + nw*32 + fn*16 + lr;
                float w = tws[trow];
                if (w != 0.f)
                    atomicAdd(out + (size_t)toks[trow] * H_DIM + col, acc[fm][fn][r] * w);
            }
}

// ---------------------------------------------------------------- fp32 fallback (small ws)
__global__ void zero_kernel(float* __restrict__ out, int n4, int* __restrict__ counts) {
    int i = blockIdx.x * blockDim.x + threadIdx.x;
    if (i < n4) {
        float4 z = {0.f, 0.f, 0.f, 0.f};
        *(float4*)(out + (size_t)i * 4) = z;
    }
    if (blockIdx.x == 0 && threadIdx.x < E_EXP) counts[threadIdx.x] = 0;
}

__global__ __launch_bounds__(256)
void router_legacy(const float* __restrict__ x, const float* __restrict__ rw,
                   const float* __restrict__ ebias, int* __restrict__ counts,
                   int* __restrict__ lists, float* __restrict__ lweights) {
    __shared__ float Xs[RTOK][H_DIM + 4];
    __shared__ float part[256];
    __shared__ float lg[RTOK][E_EXP];
    const int tid = threadIdx.x;
    const int t0 = blockIdx.x * RTOK;
    {
        int r = tid >> 5;
        int cb = (tid & 31) * 4;
        const float* xr = x + (size_t)(t0 + r) * H_DIM;
        #pragma unroll
        for (int j = 0; j < 8; ++j) {
            int c = cb + j * 128;
            *(float4*)&Xs[r][c] = *(const float4*)(xr + c);
        }
    }
    __syncthreads();
    {
        int half = tid >> 7;
        int e    = (tid >> 3) & 15;
        int tok  = tid & 7;
        const float* wr  = rw + (size_t)e * H_DIM + half * 512;
        const float* xsr = &Xs[tok][half * 512];
        float acc = 0.f;
        #pragma unroll 4
        for (int k = 0; k < 512; k += 4) {
            float4 w = *(const float4*)(wr + k);
            float4 xv = *(const float4*)(xsr + k);
            acc += w.x * xv.x + w.y * xv.y + w.z * xv.z + w.w * xv.w;
        }
        part[tid] = acc;
    }
    __syncthreads();
    if (tid < 128) {
        float logit = part[tid] + part[tid + 128];
        lg[tid & 7][(tid >> 3) & 15] = logit;
    }
    __syncthreads();
    if (tid >= RTOK) return;
    const int t = t0 + tid;
    float scores[E_EXP], sc[E_EXP];
    for (int e = 0; e < E_EXP; ++e) {
        float s = 1.f / (1.f + expf(-lg[tid][e]));
        scores[e] = s;
        sc[e] = s + ebias[e];
    }
    float gs[G_GRP];
    for (int g = 0; g < G_GRP; ++g) {
        float v[4] = { sc[g*4], sc[g*4+1], sc[g*4+2], sc[g*4+3] };
        float b1 = -1e30f; int i1 = -1;
        for (int j = 0; j < 4; ++j) if (v[j] > b1) { b1 = v[j]; i1 = j; }
        float b2 = -1e30f;
        for (int j = 0; j < 4; ++j) if (j != i1 && v[j] > b2) b2 = v[j];
        gs[g] = b1 + b2;
    }
    int g1 = -1; float b1 = -1e30f;
    for (int g = 0; g < G_GRP; ++g) if (gs[g] > b1) { b1 = gs[g]; g1 = g; }
    int g2 = -1; float b2 = -1e30f;
    for (int g = 0; g < G_GRP; ++g) if (g != g1 && gs[g] > b2) { b2 = gs[g]; g2 = g; }
    float masked[E_EXP];
    for (int e = 0; e < E_EXP; ++e) {
        int grp = e >> 2;
        masked[e] = (grp == g1 || grp == g2) ? sc[e] : 0.f;
    }
    int tidx[K_TOP]; float tw[K_TOP];
    for (int k = 0; k < K_TOP; ++k) {
        int bi = -1; float bv = -1e30f;
        for (int e = 0; e < E_EXP; ++e) if (masked[e] > bv) { bv = masked[e]; bi = e; }
        tidx[k] = bi;
        tw[k] = scores[bi];
        masked[bi] = -1e30f;
    }
    float sum = tw[0] + tw[1] + tw[2] + tw[3];
    float inv = SCALE_F / (sum + 1e-20f);
    for (int k = 0; k < K_TOP; ++k) {
        int e = tidx[k];
        int pos = atomicAdd(&counts[e], 1);
        lists[e * T_TOK + pos] = t;
        lweights[e * T_TOK + pos] = tw[k] * inv;
    }
}

__device__ __forceinline__ bfrag load_wfrag_f(const float* p) {
    float4 a = *(const float4*)(p);
    float4 b = *(const float4*)(p + 4);
    bfrag r;
    r[0]=f2bf(a.x); r[1]=f2bf(a.y); r[2]=f2bf(a.z); r[3]=f2bf(a.w);
    r[4]=f2bf(b.x); r[5]=f2bf(b.y); r[6]=f2bf(b.z); r[7]=f2bf(b.w);
    return r;
}

#define TM 32
__global__ __launch_bounds__(256)
void moe_gemm_fb(const float* __restrict__ x,
                 const float* __restrict__ gate_w, const float* __restrict__ up_w,
                 const float* __restrict__ down_w, const float* __restrict__ sh_gate,
                 const float* __restrict__ sh_up, const float* __restrict__ sh_down,
                 const int* __restrict__ counts, const int* __restrict__ lists,
                 const float* __restrict__ lweights, float* __restrict__ out) {
    const int bx = blockIdx.x;
    const int e = bx >> 6;
    const int tile = bx & 63;
    int ntok; const float *gp, *upp, *dpp; int dpitch;
    if (e < E_EXP) {
        ntok = counts[e];
        gp  = gate_w + (size_t)e * I_SZ * H_DIM;
        upp = up_w   + (size_t)e * I_SZ * H_DIM;
        dpp = down_w + (size_t)e * H_DIM * I_SZ;
        dpitch = I_SZ;
    } else {
        int s = e - E_EXP;
        ntok = T_TOK;
        gp  = sh_gate + (size_t)s * I_SZ * H_DIM;
        upp = sh_up   + (size_t)s * I_SZ * H_DIM;
        dpp = sh_down + (size_t)s * I_SZ;
        dpitch = 2 * I_SZ;
    }
    const int start = tile * TM;
    if (start >= ntok) return;

    __shared__ __align__(16) short Xs2[TM][H_DIM + 8];
    __shared__ __align__(16) short Hs2[TM][I_SZ + 8];
    __shared__ int   toks[TM];
    __shared__ float tws[TM];

    const int tid = threadIdx.x;
    if (tid < TM) {
        int j = start + tid;
        int tok = 0; float w = 0.f;
        if (j < ntok) {
            if (e < E_EXP) { tok = lists[e * T_TOK + j]; w = lweights[e * T_TOK + j]; }
            else           { tok = j;                    w = 1.0f; }
        }
        toks[tid] = tok; tws[tid] = w;
    }
    __syncthreads();
    {
        int r = tid >> 3;
        int c0 = (tid & 7) * 128;
        const float* xr = x + (size_t)toks[r] * H_DIM + c0;
        #pragma unroll
        for (int c = 0; c < 128; c += 4) {
            float4 v = *(const float4*)(xr + c);
            short4 s = { f2bf(v.x), f2bf(v.y), f2bf(v.z), f2bf(v.w) };
            *(short4*)&Xs2[r][c0 + c] = s;
        }
    }
    __syncthreads();

    const int lane = tid & 63;
    const int wv   = tid >> 6;
    const int lr   = lane & 15;
    const int lq   = lane >> 4;
    const int ko   = lq * 8;

    for (int it = 0; it < I_SZ / 64; ++it) {
        const int i0 = wv * (I_SZ / 4) + it * 16;
        const float* grow = gp  + (size_t)(i0 + lr) * H_DIM;
        const float* urow = upp + (size_t)(i0 + lr) * H_DIM;
        f32x4 aG0 = {0.f,0.f,0.f,0.f}, aU0 = {0.f,0.f,0.f,0.f};
        f32x4 aG1 = {0.f,0.f,0.f,0.f}, aU1 = {0.f,0.f,0.f,0.f};
        for (int k0 = 0; k0 < H_DIM; k0 += 32) {
            bfrag bg = load_wfrag_f(grow + k0 + ko);
            bfrag bu = load_wfrag_f(urow + k0 + ko);
            bfrag a0 = *(const bfrag*)&Xs2[lr][k0 + ko];
            bfrag a1 = *(const bfrag*)&Xs2[lr + 16][k0 + ko];
            aG0 = MFMA16(a0, bg, aG0);
            aG1 = MFMA16(a1, bg, aG1);
            aU0 = MFMA16(a0, bu, aU0);
            aU1 = MFMA16(a1, bu, aU1);
        }
        #pragma unroll
        for (int r = 0; r < 4; ++r) {
            const int trow = lq * 4 + r;
            float g0 = aG0[r], u0 = aU0[r];
            Hs2[trow][i0 + lr] = f2bf(g0 * u0 / (1.f + __expf(-g0)));
            float g1 = aG1[r], u1 = aU1[r];
            Hs2[trow + 16][i0 + lr] = f2bf(g1 * u1 / (1.f + __expf(-g1)));
        }
    }
    __syncthreads();

    for (int ct = 0; ct < H_DIM / 64; ++ct) {
        const int c0 = wv * (H_DIM / 4) + ct * 16;
        const float* drow = dpp + (size_t)(c0 + lr) * dpitch;
        f32x4 a0 = {0.f,0.f,0.f,0.f}, a1 = {0.f,0.f,0.f,0.f};
        for (int k0 = 0; k0 < I_SZ; k0 += 32) {
            bfrag bd = load_wfrag_f(drow + k0 + ko);
            bfrag h0 = *(const bfrag*)&Hs2[lr][k0 + ko];
            bfrag h1 = *(const bfrag*)&Hs2[lr + 16][k0 + ko];
            a0 = MFMA16(h0, bd, a0);
            a1 = MFMA16(h1, bd, a1);
        }
        #pragma unroll
        for (int r = 0; r < 4; ++r) {
            const int trow = lq * 4 + r;
            float w0 = tws[trow], w1 = tws[trow + 16];
            if (w0 != 0.f) atomicAdd(out + (size_t)toks[trow] * H_DIM + c0 + lr, a0[r] * w0);
            if (w1 != 0.f) atomicAdd(out + (size_t)toks[trow + 16] * H_DIM + c0 + lr, a1[r] * w1);
        }
    }
}

// ---------------------------------------------------------------- launch
extern "C" void kernel_launch(void* const* d_in, const int* in_sizes, int n_in,
                              void* d_out, int out_size, void* d_ws, size_t ws_size,
                              hipStream_t stream) {
    const float* x     = (const float*)d_in[0];
    const float* rw    = (const float*)d_in[1];
    const float* ebias = (const float*)d_in[2];
    const float* gate_w = (const float*)d_in[3];
    const float* up_w   = (const float*)d_in[4];
    const float* down_w = (const float*)d_in[5];
    const float* shg    = (const float*)d_in[6];
    const float* shu    = (const float*)d_in[7];
    const float* shd    = (const float*)d_in[8];
    float* out = (float*)d_out;

    char* ws = (char*)d_ws;
    int*   blk_cnt = (int*)ws;                        // 16 KB
    int*   blk_tok = (int*)(ws + 16384);              // 128 KB
    float* blk_wgt = (float*)(ws + 16384 + 131072);   // 128 KB
    int*   counts  = (int*)(ws + 278528);             // 1 KB
    int*   lists   = (int*)(ws + 279552);             // 128 KB
    float* lw      = (float*)(ws + 279552 + 131072);  // 128 KB
    size_t off = 279552 + 131072 + 131072;            // 541696

    const size_t n_gu = (size_t)E_EXP * I_SZ * H_DIM;   // 8388608
    const size_t n_sh = (size_t)H_DIM * 1024;           // 1048576
    const size_t n_x  = (size_t)T_TOK * H_DIM;          // 2097152

    short* g_bf  = (short*)(ws + off); off += n_gu * 2;
    short* u_bf  = (short*)(ws + off); off += n_gu * 2;
    short* d_bf  = (short*)(ws + off); off += n_gu * 2;
    short* sg_bf = (short*)(ws + off); off += n_sh * 2;
    short* su_bf = (short*)(ws + off); off += n_sh * 2;
    short* sd_bf = (short*)(ws + off); off += n_sh * 2;
    short* x_bf  = (short*)(ws + off); off += n_x * 2;
    short* h_r   = (short*)(ws + off); off += (size_t)E_EXP * T_TOK * I_SZ * 2;  // 32 MB
    short* h_sh  = (short*)(ws + off); off += (size_t)T_TOK * 1024 * 2;          // 4 MB
    const size_t need = off;

    if (ws_size >= need) {
        prep<<<256 + 3456, 256, 0, stream>>>(x, rw, ebias,
                                             gate_w, up_w, down_w, shg, shu, shd,
                                             g_bf, u_bf, d_bf, sg_bf, su_bf, sd_bf,
                                             x_bf, blk_cnt, blk_tok, blk_wgt, out);
        moe_gateup<<<512 + 4096 + 16, 256, 0, stream>>>(x_bf, blk_cnt, blk_tok, blk_wgt,
                                                        g_bf, u_bf, sg_bf, su_bf,
                                                        h_r, h_sh,
                                                        counts, lists, lw);
        moe_down<<<8192 + 512, 256, 0, stream>>>(h_r, h_sh, counts, lists, lw,
                                                 d_bf, sd_bf, out);
    } else {
        zero_kernel<<<(out_size / 4 + 255) / 256, 256, 0, stream>>>(out, out_size / 4, counts);
        router_legacy<<<T_TOK / RTOK, 256, 0, stream>>>(x, rw, ebias, counts, lists, lw);
        moe_gemm_fb<<<(E_EXP + 2) * 64, 256, 0, stream>>>(x, gate_w, up_w, down_w,
                                                          shg, shu, shd, counts, lists, lw, out);
    }
}